// Round 17
// baseline (552.368 us; speedup 1.0000x reference)
//
#include <hip/hip_runtime.h>
#include <hip/hip_bf16.h>

typedef short bf16x8 __attribute__((ext_vector_type(8)));
typedef float f32x4 __attribute__((ext_vector_type(4)));
typedef unsigned short u16;

__device__ __forceinline__ float bf2f(u16 u) {
    union { unsigned int i; float f; } x; x.i = ((unsigned int)u) << 16; return x.f;
}
__device__ __forceinline__ u16 f2bf(float f) {
    union { float f; unsigned int i; } x; x.f = f;
    unsigned int r = x.i + 0x7fff + ((x.i >> 16) & 1);
    return (u16)(r >> 16);
}
__device__ __forceinline__ f32x4 mfma16(bf16x8 a, bf16x8 b, f32x4 c) {
    return __builtin_amdgcn_mfma_f32_16x16x32_bf16(a, b, c, 0, 0, 0);
}
#define GLL16(lds_base, gsrc) \
    __builtin_amdgcn_global_load_lds((const __attribute__((address_space(1))) void*)(gsrc), \
                                     (__attribute__((address_space(3))) void*)(lds_base), 16, 0, 0)

// ------------- fused transpose of five 1024x1024 weights ----------------
__global__ __launch_bounds__(256)
void transpose5_kernel(const float* __restrict__ s0, const float* __restrict__ s1,
                       const float* __restrict__ s2, const float* __restrict__ s3,
                       const float* __restrict__ s4,
                       u16* __restrict__ d0, u16* __restrict__ d1,
                       u16* __restrict__ d2, u16* __restrict__ d3,
                       u16* __restrict__ d4) {
    const float* in; u16* out;
    switch (blockIdx.z) {
        case 0: in = s0; out = d0; break;
        case 1: in = s1; out = d1; break;
        case 2: in = s2; out = d2; break;
        case 3: in = s3; out = d3; break;
        default: in = s4; out = d4; break;
    }
    __shared__ float t[32][33];
    const int c0 = blockIdx.x * 32, r0 = blockIdx.y * 32;
    const int tx = threadIdx.x & 31, ty = threadIdx.x >> 5;
#pragma unroll
    for (int i = 0; i < 32; i += 8) t[ty + i][tx] = in[(size_t)(r0 + ty + i) * 1024 + c0 + tx];
    __syncthreads();
#pragma unroll
    for (int i = 0; i < 32; i += 8) out[(size_t)(c0 + ty + i) * 1024 + r0 + tx] = f2bf(t[tx][ty + i]);
}

// ------------- transpose fp32 [R][C] -> bf16 [C][R] ---------------------
__global__ __launch_bounds__(256)
void transpose_kernel(const float* __restrict__ in, u16* __restrict__ out, int R, int C) {
    __shared__ float t[32][33];
    const int c0 = blockIdx.x * 32, r0 = blockIdx.y * 32;
    const int tx = threadIdx.x & 31, ty = threadIdx.x >> 5;
#pragma unroll
    for (int i = 0; i < 32; i += 8) t[ty + i][tx] = in[(size_t)(r0 + ty + i) * C + c0 + tx];
    __syncthreads();
#pragma unroll
    for (int i = 0; i < 32; i += 8) out[(size_t)(c0 + ty + i) * R + r0 + tx] = f2bf(t[tx][ty + i]);
}

// ------------- fp32 -> bf16 convert (8 elems/thread) --------------------
__global__ __launch_bounds__(256)
void convert_kernel(const float* __restrict__ in, u16* __restrict__ out) {
    const size_t i = ((size_t)blockIdx.x * 256 + threadIdx.x) * 8;
    const float4 a = *(const float4*)(in + i);
    const float4 b = *(const float4*)(in + i + 4);
    bf16x8 o;
    o[0] = (short)f2bf(a.x); o[1] = (short)f2bf(a.y);
    o[2] = (short)f2bf(a.z); o[3] = (short)f2bf(a.w);
    o[4] = (short)f2bf(b.x); o[5] = (short)f2bf(b.y);
    o[6] = (short)f2bf(b.z); o[7] = (short)f2bf(b.w);
    *(bf16x8*)(out + i) = o;
}

// ------------- positional embedding pe[2048][1024] (bf16) ---------------
__global__ __launch_bounds__(256)
void pe_kernel(u16* __restrict__ pe) {
    const int idx = blockIdx.x * 256 + threadIdx.x;
    const int p = idx >> 10, d = idx & 1023;
    const float pos = (float)(2047 - p);
    const int k = d & 511;
    const float invf = powf(10000.f, ((float)(2 * k)) * (-1.f / 1024.f));
    const float a = pos * invf;
    pe[idx] = f2bf((d < 512) ? sinf(a) : cosf(a));
}

// ------------- LayerNorm (fp32 in, bf16 out), one wave per row ----------
__global__ __launch_bounds__(256)
void ln_kernel(const float* __restrict__ inp, const float* __restrict__ gg,
               const float* __restrict__ bb, u16* __restrict__ outp) {
    const int row = blockIdx.x * 4 + (threadIdx.x >> 6);
    const int l = threadIdx.x & 63;
    const size_t base = (size_t)row * 1024 + l * 16;
    float v[16];
    const float4* p4 = (const float4*)(inp + base);
#pragma unroll
    for (int j = 0; j < 4; ++j) {
        float4 f = p4[j];
        v[j*4+0] = f.x; v[j*4+1] = f.y; v[j*4+2] = f.z; v[j*4+3] = f.w;
    }
    float s = 0.f, s2 = 0.f;
#pragma unroll
    for (int j = 0; j < 16; ++j) { s += v[j]; s2 += v[j] * v[j]; }
#pragma unroll
    for (int off = 1; off < 64; off <<= 1) {
        s += __shfl_xor(s, off, 64);
        s2 += __shfl_xor(s2, off, 64);
    }
    const float mu = s * 0.0009765625f;
    const float var = s2 * 0.0009765625f - mu * mu;
    const float rs = rsqrtf(var + 1e-5f);
#pragma unroll
    for (int j = 0; j < 16; ++j)
        outp[base + j] = f2bf((v[j] - mu) * rs * gg[l * 16 + j] + bb[l * 16 + j]);
}

// ---------------- GEMM 128x128 (FF1): proven m97 structure --------------
template<int EPI, bool CATA>
__global__ __launch_bounds__(256)
void gemm_kernel(const u16* __restrict__ A, const u16* __restrict__ A2,
                 const u16* __restrict__ Wt, void* __restrict__ outp,
                 u16* __restrict__ out2, const float* __restrict__ cb1,
                 const float* __restrict__ cb2, const float* __restrict__ residp,
                 int Mdim, int Ndim, int Kdim) {
    __shared__ __attribute__((aligned(16))) u16 As[128 * 32];
    __shared__ __attribute__((aligned(16))) u16 Bs[128 * 32];
    const int tid = threadIdx.x;
    const int w = tid >> 6, l = tid & 63;
    const int wr = w >> 1, wc = w & 1;
    const int m0 = blockIdx.x * 128, n0 = blockIdx.y * 128;
    f32x4 acc[4][4] = {};

    for (int k0 = 0; k0 < Kdim; k0 += 32) {
        __syncthreads();
#pragma unroll
        for (int p = 0; p < 2; ++p) {
            const int ebase = (p * 4 + w) * 512;
            const int e = ebase + l * 8;
            const int row = e >> 5, colk = e & 31;
            const u16* srcA;
            if (CATA) {
                const int rr = m0 + row;
                const int bb_ = rr >> 11, pos = rr & 2047;
                srcA = (pos < 1024 ? A + ((size_t)(bb_ * 1024 + pos)) * 1024
                                   : A2 + ((size_t)(bb_ * 1024 + pos - 1024)) * 1024)
                       + (k0 + colk);
            } else {
                srcA = A + (size_t)(m0 + row) * Kdim + (k0 + colk);
            }
            const u16* srcB = Wt + (size_t)(n0 + row) * Kdim + (k0 + colk);
            GLL16(&As[ebase], srcA);
            GLL16(&Bs[ebase], srcB);
        }
        __syncthreads();
        bf16x8 af[4], bfr[4];
#pragma unroll
        for (int mi = 0; mi < 4; ++mi)
            af[mi] = *(const bf16x8*)&As[(wr * 64 + mi * 16 + (l & 15)) * 32 + (l >> 4) * 8];
#pragma unroll
        for (int ni = 0; ni < 4; ++ni)
            bfr[ni] = *(const bf16x8*)&Bs[(wc * 64 + ni * 16 + (l & 15)) * 32 + (l >> 4) * 8];
#pragma unroll
        for (int mi = 0; mi < 4; ++mi)
#pragma unroll
            for (int ni = 0; ni < 4; ++ni)
                acc[mi][ni] = mfma16(af[mi], bfr[ni], acc[mi][ni]);
    }

#pragma unroll
    for (int mi = 0; mi < 4; ++mi)
#pragma unroll
        for (int ni = 0; ni < 4; ++ni)
#pragma unroll
            for (int rg = 0; rg < 4; ++rg) {
                const int row = m0 + wr * 64 + mi * 16 + (l >> 4) * 4 + rg;
                const int col = n0 + wc * 64 + ni * 16 + (l & 15);
                const size_t idx = (size_t)row * Ndim + col;
                const float v = acc[mi][ni][rg];
                if (EPI == 0) {
                    ((u16*)outp)[idx] = f2bf(v);
                } else if (EPI == 1) {
                    ((u16*)outp)[idx] = f2bf(v + cb1[col]);
                    out2[idx] = f2bf(v + cb2[col]);
                } else if (EPI == 2) {
                    ((float*)outp)[idx] = v + residp[idx];
                } else if (EPI == 3) {
                    const float t = v + cb1[col];
                    ((u16*)outp)[idx] = f2bf(0.5f * t * (1.f + erff(t * 0.70710678118654752f)));
                } else {
                    ((float*)outp)[idx] = v + cb1[col] + residp[idx]; // fp32 y
                }
            }
}

// ---------------- GEMM 64x128 (narrow-N GEMMs): 2x block count ----------
template<int EPI>
__global__ __launch_bounds__(256)
void gemm64_kernel(const u16* __restrict__ A, const u16* __restrict__ Wt,
                   void* __restrict__ outp, u16* __restrict__ out2,
                   const float* __restrict__ cb1, const float* __restrict__ cb2,
                   const float* __restrict__ residp,
                   int Mdim, int Ndim, int Kdim) {
    __shared__ __attribute__((aligned(16))) u16 As[64 * 32];
    __shared__ __attribute__((aligned(16))) u16 Bs[128 * 32];
    const int tid = threadIdx.x;
    const int w = tid >> 6, l = tid & 63;
    const int m0 = blockIdx.x * 64, n0 = blockIdx.y * 128;
    f32x4 acc[4][2] = {};

    for (int k0 = 0; k0 < Kdim; k0 += 32) {
        __syncthreads();
        {
            const int e = (w * 64 + l) * 8;
            const int row = e >> 5, colk = e & 31;
            GLL16(&As[w * 512], A + (size_t)(m0 + row) * Kdim + (k0 + colk));
        }
#pragma unroll
        for (int p = 0; p < 2; ++p) {
            const int ebase = (p * 4 + w) * 512;
            const int e = ebase + l * 8;
            const int row = e >> 5, colk = e & 31;
            GLL16(&Bs[ebase], Wt + (size_t)(n0 + row) * Kdim + (k0 + colk));
        }
        __syncthreads();
        bf16x8 af[4], bfr[2];
#pragma unroll
        for (int mi = 0; mi < 4; ++mi)
            af[mi] = *(const bf16x8*)&As[(mi * 16 + (l & 15)) * 32 + (l >> 4) * 8];
#pragma unroll
        for (int ni = 0; ni < 2; ++ni)
            bfr[ni] = *(const bf16x8*)&Bs[(w * 32 + ni * 16 + (l & 15)) * 32 + (l >> 4) * 8];
#pragma unroll
        for (int mi = 0; mi < 4; ++mi)
#pragma unroll
            for (int ni = 0; ni < 2; ++ni)
                acc[mi][ni] = mfma16(af[mi], bfr[ni], acc[mi][ni]);
    }

#pragma unroll
    for (int mi = 0; mi < 4; ++mi)
#pragma unroll
        for (int ni = 0; ni < 2; ++ni)
#pragma unroll
            for (int rg = 0; rg < 4; ++rg) {
                const int row = m0 + mi * 16 + (l >> 4) * 4 + rg;
                const int col = n0 + w * 32 + ni * 16 + (l & 15);
                const size_t idx = (size_t)row * Ndim + col;
                const float v = acc[mi][ni][rg];
                if (EPI == 0) {
                    ((u16*)outp)[idx] = f2bf(v);
                } else if (EPI == 1) {
                    ((u16*)outp)[idx] = f2bf(v + cb1[col]);
                    out2[idx] = f2bf(v + cb2[col]);
                } else if (EPI == 2) {
                    ((float*)outp)[idx] = v + residp[idx];
                } else {
                    ((float*)outp)[idx] = v + cb1[col] + residp[idx]; // fp32 y
                }
            }
}

// ---------------- fused K+V GEMM: stage A once, compute both ------------
__global__ __launch_bounds__(256)
void gemm_kv_kernel(const u16* __restrict__ A, const u16* __restrict__ A2,
                    const u16* __restrict__ WtK, const u16* __restrict__ WtV,
                    u16* __restrict__ outK, u16* __restrict__ outV) {
    __shared__ __attribute__((aligned(16))) u16 As[128 * 32];
    __shared__ __attribute__((aligned(16))) u16 Bk[128 * 32];
    __shared__ __attribute__((aligned(16))) u16 Bv[128 * 32];
    const int tid = threadIdx.x;
    const int w = tid >> 6, l = tid & 63;
    const int wr = w >> 1, wc = w & 1;
    const int m0 = blockIdx.x * 128, n0 = blockIdx.y * 128;
    f32x4 acck[4][4] = {};
    f32x4 accv[4][4] = {};

    for (int k0 = 0; k0 < 1024; k0 += 32) {
        __syncthreads();
#pragma unroll
        for (int p = 0; p < 2; ++p) {
            const int ebase = (p * 4 + w) * 512;
            const int e = ebase + l * 8;
            const int row = e >> 5, colk = e & 31;
            const int rr = m0 + row;
            const int bb_ = rr >> 11, pos = rr & 2047;
            const u16* srcA = (pos < 1024 ? A + ((size_t)(bb_ * 1024 + pos)) * 1024
                                          : A2 + ((size_t)(bb_ * 1024 + pos - 1024)) * 1024)
                              + (k0 + colk);
            GLL16(&As[ebase], srcA);
            GLL16(&Bk[ebase], WtK + (size_t)(n0 + row) * 1024 + (k0 + colk));
            GLL16(&Bv[ebase], WtV + (size_t)(n0 + row) * 1024 + (k0 + colk));
        }
        __syncthreads();
        bf16x8 af[4], bkf[4], bvf[4];
#pragma unroll
        for (int mi = 0; mi < 4; ++mi)
            af[mi] = *(const bf16x8*)&As[(wr * 64 + mi * 16 + (l & 15)) * 32 + (l >> 4) * 8];
#pragma unroll
        for (int ni = 0; ni < 4; ++ni) {
            const int off = (wc * 64 + ni * 16 + (l & 15)) * 32 + (l >> 4) * 8;
            bkf[ni] = *(const bf16x8*)&Bk[off];
            bvf[ni] = *(const bf16x8*)&Bv[off];
        }
#pragma unroll
        for (int mi = 0; mi < 4; ++mi)
#pragma unroll
            for (int ni = 0; ni < 4; ++ni) {
                acck[mi][ni] = mfma16(af[mi], bkf[ni], acck[mi][ni]);
                accv[mi][ni] = mfma16(af[mi], bvf[ni], accv[mi][ni]);
            }
    }

#pragma unroll
    for (int mi = 0; mi < 4; ++mi)
#pragma unroll
        for (int ni = 0; ni < 4; ++ni)
#pragma unroll
            for (int rg = 0; rg < 4; ++rg) {
                const int row = m0 + wr * 64 + mi * 16 + (l >> 4) * 4 + rg;
                const int col = n0 + wc * 64 + ni * 16 + (l & 15);
                const size_t idx = (size_t)row * 1024 + col;
                outK[idx] = f2bf(acck[mi][ni][rg]);
                outV[idx] = f2bf(accv[mi][ni][rg]);
            }
}

// ---------------- fused rel-attention: single shared R buffer -----------
// main_blk/wrap_blk are BLOCK-uniform and overlap for only 2-3 of 32 jt;
// one 16KB R buffer serves both bands (two-phase restage on overlap tiles).
// LDS 43KB -> 3 blocks/CU (occupancy 22% -> 33%).
__global__ __launch_bounds__(256, 3)
void attn_kernel(const u16* __restrict__ qu, const u16* __restrict__ qv,
                 const u16* __restrict__ kcat, const u16* __restrict__ vcat,
                 const u16* __restrict__ rbuf, u16* __restrict__ outp) {
    constexpr int T = 1024, L = 2048, MM = 1024;
    __shared__ __attribute__((aligned(16))) u16 KtL[64 * 64];   // 8KB swz
    __shared__ __attribute__((aligned(16))) u16 RL[128 * 64];   // 16KB swz (shared)
    __shared__ __attribute__((aligned(16))) u16 Vt[64][72];     // 9KB (j' cols)
    __shared__ __attribute__((aligned(16))) u16 Pl[4][16][72];  // 9KB (j' cols)
    const int bid = blockIdx.x;
    const int g = (bid & 7) + 8 * (bid >> 7);   // head-group (XCD swizzle)
    const int it = (bid >> 3) & 15;
    const int h = g & 15, b = g >> 4;
    const int i0 = it * 64;
    const int tid = threadIdx.x;
    const int w = tid >> 6, l = tid & 63;
    const int lg = l >> 4, ll = l & 15;
    const int iw0 = i0 + w * 16;
    const int l8 = l >> 3;
    const int ssrc = ((l & 7) * 8) ^ (l8 << 3);
    const int sA = (lg * 8) ^ ((ll & 7) << 3);
    const int sB = (lg * 8 + 32) ^ ((ll & 7) << 3);

    bf16x8 quf[2], qvf[2];
    const int qc = h * 64 + lg * 8;
    {
        const size_t qrow = (size_t)(b * T + iw0 + ll);
        quf[0] = *(const bf16x8*)&qu[qrow * 1024 + qc];
        quf[1] = *(const bf16x8*)&qu[qrow * 1024 + qc + 32];
        qvf[0] = *(const bf16x8*)&qv[qrow * 1024 + qc];
        qvf[1] = *(const bf16x8*)&qv[qrow * 1024 + qc + 32];
    }
    const int r2 = iw0 + ll + 1;
    const size_t qrow2 = (size_t)(b * T + (r2 < T ? r2 : T - 1));
    const u16* kb = kcat + (size_t)b * L * 1024 + h * 64;
    const u16* vb = vcat + (size_t)b * L * 1024 + h * 64;
    const u16* rb = rbuf + h * 64;

    f32x4 o_acc[4] = {};
    f32x4 o_sum = {0.f, 0.f, 0.f, 0.f};
    float m_run[4] = {-1e30f, -1e30f, -1e30f, -1e30f};
    const bf16x8 onesb = {(short)0x3F80, (short)0x3F80, (short)0x3F80, (short)0x3F80,
                          (short)0x3F80, (short)0x3F80, (short)0x3F80, (short)0x3F80};
    const int vjq = tid & 15, vdg = tid >> 4;

    for (int jt = 0; jt < 32; ++jt) {
        const int j0 = jt * 64;
        const bool main_blk = (j0 <= MM + i0 + 63);
        const bool wrap_blk = (j0 + 63 >= MM + i0 + 2);
        __syncthreads();
        // ---- stage K, V, and first R band (main if present, else wrap) ----
#pragma unroll
        for (int p = 0; p < 2; ++p) {
            const int k8 = w * 2 + p;
            GLL16(&KtL[k8 * 512], kb + (size_t)(j0 + k8 * 8 + l8) * 1024 + ssrc);
        }
        if (main_blk) {
            const long bm = (long)j0 + T - i0 - 64;
#pragma unroll
            for (int p = 0; p < 4; ++p) {
                const int k8 = w * 4 + p;
                GLL16(&RL[k8 * 512], rb + (long)(bm + k8 * 8 + l8) * 1024 + ssrc);
            }
        } else if (wrap_blk) {
            const long bw_ = (long)j0 - MM - i0 - 65;
#pragma unroll
            for (int p = 0; p < 4; ++p) {
                const int k8 = w * 4 + p;
                GLL16(&RL[k8 * 512], rb + (long)(bw_ + k8 * 8 + l8) * 1024 + ssrc);
            }
        }
        { // V^T stage with j-permutation: rows j = vjq + 16s -> j' = 4*vjq+s
            const u16* srcv = vb + (size_t)(j0 + vjq) * 1024 + vdg * 4;
            const ushort4 r0 = *(const ushort4*)(srcv);
            const ushort4 r1 = *(const ushort4*)(srcv + 16 * 1024);
            const ushort4 r2w = *(const ushort4*)(srcv + 32 * 1024);
            const ushort4 r3 = *(const ushort4*)(srcv + 48 * 1024);
            const ushort4 c0 = {r0.x, r1.x, r2w.x, r3.x};
            const ushort4 c1 = {r0.y, r1.y, r2w.y, r3.y};
            const ushort4 c2 = {r0.z, r1.z, r2w.z, r3.z};
            const ushort4 c3 = {r0.w, r1.w, r2w.w, r3.w};
            *(ushort4*)&Vt[vdg * 4 + 0][vjq * 4] = c0;
            *(ushort4*)&Vt[vdg * 4 + 1][vjq * 4] = c1;
            *(ushort4*)&Vt[vdg * 4 + 2][vjq * 4] = c2;
            *(ushort4*)&Vt[vdg * 4 + 3][vjq * 4] = c3;
        }
        __syncthreads();

        // ---- content scores ----
        f32x4 sv[4];
        __builtin_amdgcn_s_setprio(1);
#pragma unroll
        for (int ns = 0; ns < 4; ++ns) {
            const int rowb = (ns * 16 + ll) * 64;
            f32x4 a = {0.f, 0.f, 0.f, 0.f};
            a = mfma16(quf[0], *(const bf16x8*)&KtL[rowb + sA], a);
            a = mfma16(quf[1], *(const bf16x8*)&KtL[rowb + sB], a);
            sv[ns] = a;
        }
        __builtin_amdgcn_s_setprio(0);

        // ---- main band from RL ----
        if (main_blk && j0 <= MM + iw0 + 15) {
            const int trb = 48 - 16 * w;
            f32x4 gb[5];
#pragma unroll
            for (int cs = 0; cs < 5; ++cs) {
                const int rowb = (trb + cs * 16 + ll) * 64;
                f32x4 a = {0.f, 0.f, 0.f, 0.f};
                a = mfma16(qvf[0], *(const bf16x8*)&RL[rowb + sA], a);
                a = mfma16(qvf[1], *(const bf16x8*)&RL[rowb + sB], a);
                gb[cs] = a;
            }
#pragma unroll
            for (int r = 0; r < 4; ++r) {
                const int i_loc = lg * 4 + r;
                const int srcl = (l & 48) | ((ll + 15 - i_loc) & 15);
                const float sh0 = __shfl(gb[0][r], srcl, 64);
                const float sh1 = __shfl(gb[1][r], srcl, 64);
                const float sh2 = __shfl(gb[2][r], srcl, 64);
                const float sh3 = __shfl(gb[3][r], srcl, 64);
                const float sh4 = __shfl(gb[4][r], srcl, 64);
                const bool hi = (ll > i_loc);
                const int thr = MM + iw0 + i_loc - j0;
                const float e0 = hi ? sh1 : sh0;
                const float e1 = hi ? sh2 : sh1;
                const float e2 = hi ? sh3 : sh2;
                const float e3 = hi ? sh4 : sh3;
                if (ll <= thr)      sv[0][r] += e0;
                if (16 + ll <= thr) sv[1][r] += e1;
                if (32 + ll <= thr) sv[2][r] += e2;
                if (48 + ll <= thr) sv[3][r] += e3;
            }
        }
        // ---- wrap band: restage RL if main occupied it (block-uniform) ----
        if (wrap_blk) {
            if (main_blk) {
                __syncthreads();   // everyone done reading main RL
                const long bw_ = (long)j0 - MM - i0 - 65;
#pragma unroll
                for (int p = 0; p < 4; ++p) {
                    const int k8 = w * 4 + p;
                    GLL16(&RL[k8 * 512], rb + (long)(bw_ + k8 * 8 + l8) * 1024 + ssrc);
                }
                __syncthreads();
            }
            if (j0 + 63 >= MM + iw0 + 2) {
                const bf16x8 qv2f0 = *(const bf16x8*)&qv[qrow2 * 1024 + qc];
                const bf16x8 qv2f1 = *(const bf16x8*)&qv[qrow2 * 1024 + qc + 32];
                const int trb = 48 - 16 * w;
                f32x4 gb[5];
#pragma unroll
                for (int cs = 0; cs < 5; ++cs) {
                    const int rowb = (trb + cs * 16 + ll) * 64;
                    f32x4 a = {0.f, 0.f, 0.f, 0.f};
                    a = mfma16(qv2f0, *(const bf16x8*)&RL[rowb + sA], a);
                    a = mfma16(qv2f1, *(const bf16x8*)&RL[rowb + sB], a);
                    gb[cs] = a;
                }
#pragma unroll
                for (int r = 0; r < 4; ++r) {
                    const int i_loc = lg * 4 + r;
                    const int srcl = (l & 48) | ((ll + 15 - i_loc) & 15);
                    const float sh0 = __shfl(gb[0][r], srcl, 64);
                    const float sh1 = __shfl(gb[1][r], srcl, 64);
                    const float sh2 = __shfl(gb[2][r], srcl, 64);
                    const float sh3 = __shfl(gb[3][r], srcl, 64);
                    const float sh4 = __shfl(gb[4][r], srcl, 64);
                    const bool hi = (ll > i_loc);
                    const int thr2 = MM + iw0 + i_loc - j0 + 2;
                    const float e0 = hi ? sh1 : sh0;
                    const float e1 = hi ? sh2 : sh1;
                    const float e2 = hi ? sh3 : sh2;
                    const float e3 = hi ? sh4 : sh3;
                    if (ll >= thr2)      sv[0][r] += e0;
                    if (16 + ll >= thr2) sv[1][r] += e1;
                    if (32 + ll >= thr2) sv[2][r] += e2;
                    if (48 + ll >= thr2) sv[3][r] += e3;
                }
            }
        }

        // ---- online softmax (max only; sums via ones-MFMA) + packed P ----
#pragma unroll
        for (int r = 0; r < 4; ++r) {
            const int i_loc = lg * 4 + r;
            const float s0 = sv[0][r] * 0.125f, s1 = sv[1][r] * 0.125f;
            const float s2 = sv[2][r] * 0.125f, s3 = sv[3][r] * 0.125f;
            float pm = fmaxf(fmaxf(s0, s1), fmaxf(s2, s3));
            pm = fmaxf(pm, __shfl_xor(pm, 1, 64));
            pm = fmaxf(pm, __shfl_xor(pm, 2, 64));
            pm = fmaxf(pm, __shfl_xor(pm, 4, 64));
            pm = fmaxf(pm, __shfl_xor(pm, 8, 64));
            const float mnew = fmaxf(m_run[r], pm);
            const float alpha = __expf(m_run[r] - mnew);
            const float p0 = __expf(s0 - mnew), p1 = __expf(s1 - mnew);
            const float p2 = __expf(s2 - mnew), p3 = __expf(s3 - mnew);
            const ushort4 pw = {f2bf(p0), f2bf(p1), f2bf(p2), f2bf(p3)};
            *(ushort4*)&Pl[w][i_loc][ll * 4] = pw;
            m_run[r] = mnew;
            o_sum[r] *= alpha;
#pragma unroll
            for (int ns = 0; ns < 4; ++ns) o_acc[ns][r] *= alpha;
        }

        // ---- O += P @ V (j'-order); denominators via ones-B ----
        __builtin_amdgcn_s_setprio(1);
        const bf16x8 ap0 = *(const bf16x8*)&Pl[w][ll][lg * 8];
        const bf16x8 ap1 = *(const bf16x8*)&Pl[w][ll][32 + lg * 8];
#pragma unroll
        for (int ns = 0; ns < 4; ++ns) {
            const bf16x8 bv0 = *(const bf16x8*)&Vt[ns * 16 + ll][lg * 8];
            const bf16x8 bv1 = *(const bf16x8*)&Vt[ns * 16 + ll][32 + lg * 8];
            o_acc[ns] = mfma16(ap0, bv0, o_acc[ns]);
            o_acc[ns] = mfma16(ap1, bv1, o_acc[ns]);
        }
        o_sum = mfma16(ap0, onesb, o_sum);
        o_sum = mfma16(ap1, onesb, o_sum);
        __builtin_amdgcn_s_setprio(0);
    }

#pragma unroll
    for (int ns = 0; ns < 4; ++ns)
#pragma unroll
        for (int r = 0; r < 4; ++r) {
            const int row = iw0 + lg * 4 + r;
            outp[(size_t)(b * T + row) * 1024 + h * 64 + ns * 16 + ll] =
                f2bf(o_acc[ns][r] / o_sum[r]);
        }
}

// ------------------------------- launch ---------------------------------
extern "C" void kernel_launch(void* const* d_in, const int* in_sizes, int n_in,
                              void* d_out, int out_size, void* d_ws, size_t ws_size,
                              hipStream_t stream) {
    const float* x    = (const float*)d_in[0];
    const float* mem  = (const float*)d_in[1];
    const float* Wq   = (const float*)d_in[2];
    const float* Wk   = (const float*)d_in[3];
    const float* Wv   = (const float*)d_in[4];
    const float* Wr   = (const float*)d_in[5];
    const float* Wo   = (const float*)d_in[6];
    const float* bu   = (const float*)d_in[7];
    const float* bv   = (const float*)d_in[8];
    const float* ln1g = (const float*)d_in[9];
    const float* ln1b = (const float*)d_in[10];
    const float* ln2g = (const float*)d_in[11];
    const float* ln2b = (const float*)d_in[12];
    const float* W1   = (const float*)d_in[13];
    const float* b1   = (const float*)d_in[14];
    const float* W2   = (const float*)d_in[15];
    const float* b2   = (const float*)d_in[16];

    float* y_out   = (float*)d_out;
    float* mem_out = (float*)d_out + 4194304;

    // ===== d_out (32 MB fp32) as scratch, time-multiplexed =====
    char* dob = (char*)d_out;
    u16* attno     = (u16*)(dob + 0);
    u16* pe        = (u16*)(dob + (size_t)8  * 1048576);
    u16* rbuf_base = (u16*)(dob + (size_t)12 * 1048576);
    u16* rbuf      = rbuf_base + 80 * 1024;           // padded +/-80 rows
    char* dw = dob + (size_t)16 * 1048576 + 524288;   // 16.5 MB
    u16* WqT = (u16*)(dw);
    u16* WkT = (u16*)(dw + (size_t)2 * 1048576);
    u16* WvT = (u16*)(dw + (size_t)4 * 1048576);
    u16* WrT = (u16*)(dw + (size_t)6 * 1048576);
    u16* WoT = (u16*)(dw + (size_t)8 * 1048576);

    // ===== ws layout, extent 64 MB =====
    char* ws = (char*)d_ws;
    const size_t MB = 1u << 20;
    u16*  xn    = (u16*)(ws + 0 * MB);
    u16*  x2n   = (u16*)(ws + 0 * MB);
    u16*  W2T   = (u16*)(ws + 0 * MB);
    u16*  qu    = (u16*)(ws + 8 * MB);
    float* x2f  = (float*)(ws + 8 * MB);
    u16*  qv    = (u16*)(ws + 16 * MB);
    u16*  kcat  = (u16*)(ws + 24 * MB);
    u16*  ffh   = (u16*)(ws + 24 * MB);
    u16*  vcat  = (u16*)(ws + 40 * MB);
    u16*  memb  = (u16*)(ws + 56 * MB);
    u16*  W1T   = (u16*)(ws + 56 * MB);

    transpose5_kernel<<<dim3(32, 32, 5), 256, 0, stream>>>(Wq, Wk, Wv, Wr, Wo,
                                                           WqT, WkT, WvT, WrT, WoT);
    pe_kernel<<<8192, 256, 0, stream>>>(pe);
    convert_kernel<<<2048, 256, 0, stream>>>(mem, memb);
    ln_kernel<<<1024, 256, 0, stream>>>(x, ln1g, ln1b, xn);
    gemm64_kernel<0><<<dim3(32, 8), 256, 0, stream>>>(pe, WrT, rbuf, nullptr, nullptr, nullptr, nullptr, 2048, 1024, 1024);
    gemm64_kernel<1><<<dim3(64, 8), 256, 0, stream>>>(xn, WqT, qu, qv, bu, bv, nullptr, 4096, 1024, 1024);
    gemm_kv_kernel<<<dim3(64, 8), 256, 0, stream>>>(memb, xn, WkT, WvT, kcat, vcat);
    attn_kernel<<<1024, 256, 0, stream>>>(qu, qv, kcat, vcat, rbuf, attno);
    gemm64_kernel<2><<<dim3(64, 8), 256, 0, stream>>>(attno, WoT, x2f, nullptr, nullptr, nullptr, x, 4096, 1024, 1024);
    transpose_kernel<<<dim3(128, 32), 256, 0, stream>>>(W1, W1T, 1024, 4096);
    hipMemcpyAsync(mem_out, x, (size_t)4194304 * 4, hipMemcpyDeviceToDevice, stream);
    ln_kernel<<<1024, 256, 0, stream>>>(x2f, ln2g, ln2b, x2n);
    gemm_kernel<3, false><<<dim3(32, 32), 256, 0, stream>>>(x2n, nullptr, W1T, ffh, nullptr, b1, nullptr, nullptr, 4096, 4096, 1024);
    transpose_kernel<<<dim3(32, 128), 256, 0, stream>>>(W2, W2T, 4096, 1024);
    gemm64_kernel<4><<<dim3(64, 8), 256, 0, stream>>>(ffh, W2T, y_out, nullptr, b2, nullptr, x2f, 4096, 1024, 4096);
    (void)in_sizes; (void)n_in; (void)out_size; (void)ws_size;
}

// Round 18
// 539.634 us; speedup vs baseline: 1.0236x; 1.0236x over previous
//
#include <hip/hip_runtime.h>
#include <hip/hip_bf16.h>

typedef short bf16x8 __attribute__((ext_vector_type(8)));
typedef float f32x4 __attribute__((ext_vector_type(4)));
typedef unsigned short u16;

__device__ __forceinline__ float bf2f(u16 u) {
    union { unsigned int i; float f; } x; x.i = ((unsigned int)u) << 16; return x.f;
}
__device__ __forceinline__ u16 f2bf(float f) {
    union { float f; unsigned int i; } x; x.f = f;
    unsigned int r = x.i + 0x7fff + ((x.i >> 16) & 1);
    return (u16)(r >> 16);
}
__device__ __forceinline__ f32x4 mfma16(bf16x8 a, bf16x8 b, f32x4 c) {
    return __builtin_amdgcn_mfma_f32_16x16x32_bf16(a, b, c, 0, 0, 0);
}
#define GLL16(lds_base, gsrc) \
    __builtin_amdgcn_global_load_lds((const __attribute__((address_space(1))) void*)(gsrc), \
                                     (__attribute__((address_space(3))) void*)(lds_base), 16, 0, 0)

// ------------- fused transpose of five 1024x1024 weights ----------------
__global__ __launch_bounds__(256)
void transpose5_kernel(const float* __restrict__ s0, const float* __restrict__ s1,
                       const float* __restrict__ s2, const float* __restrict__ s3,
                       const float* __restrict__ s4,
                       u16* __restrict__ d0, u16* __restrict__ d1,
                       u16* __restrict__ d2, u16* __restrict__ d3,
                       u16* __restrict__ d4) {
    const float* in; u16* out;
    switch (blockIdx.z) {
        case 0: in = s0; out = d0; break;
        case 1: in = s1; out = d1; break;
        case 2: in = s2; out = d2; break;
        case 3: in = s3; out = d3; break;
        default: in = s4; out = d4; break;
    }
    __shared__ float t[32][33];
    const int c0 = blockIdx.x * 32, r0 = blockIdx.y * 32;
    const int tx = threadIdx.x & 31, ty = threadIdx.x >> 5;
#pragma unroll
    for (int i = 0; i < 32; i += 8) t[ty + i][tx] = in[(size_t)(r0 + ty + i) * 1024 + c0 + tx];
    __syncthreads();
#pragma unroll
    for (int i = 0; i < 32; i += 8) out[(size_t)(c0 + ty + i) * 1024 + r0 + tx] = f2bf(t[tx][ty + i]);
}

// ------------- transpose fp32 [R][C] -> bf16 [C][R] ---------------------
__global__ __launch_bounds__(256)
void transpose_kernel(const float* __restrict__ in, u16* __restrict__ out, int R, int C) {
    __shared__ float t[32][33];
    const int c0 = blockIdx.x * 32, r0 = blockIdx.y * 32;
    const int tx = threadIdx.x & 31, ty = threadIdx.x >> 5;
#pragma unroll
    for (int i = 0; i < 32; i += 8) t[ty + i][tx] = in[(size_t)(r0 + ty + i) * C + c0 + tx];
    __syncthreads();
#pragma unroll
    for (int i = 0; i < 32; i += 8) out[(size_t)(c0 + ty + i) * R + r0 + tx] = f2bf(t[tx][ty + i]);
}

// ------------- fp32 -> bf16 convert (8 elems/thread) --------------------
__global__ __launch_bounds__(256)
void convert_kernel(const float* __restrict__ in, u16* __restrict__ out) {
    const size_t i = ((size_t)blockIdx.x * 256 + threadIdx.x) * 8;
    const float4 a = *(const float4*)(in + i);
    const float4 b = *(const float4*)(in + i + 4);
    bf16x8 o;
    o[0] = (short)f2bf(a.x); o[1] = (short)f2bf(a.y);
    o[2] = (short)f2bf(a.z); o[3] = (short)f2bf(a.w);
    o[4] = (short)f2bf(b.x); o[5] = (short)f2bf(b.y);
    o[6] = (short)f2bf(b.z); o[7] = (short)f2bf(b.w);
    *(bf16x8*)(out + i) = o;
}

// ------------- positional embedding pe[2048][1024] (bf16) ---------------
__global__ __launch_bounds__(256)
void pe_kernel(u16* __restrict__ pe) {
    const int idx = blockIdx.x * 256 + threadIdx.x;
    const int p = idx >> 10, d = idx & 1023;
    const float pos = (float)(2047 - p);
    const int k = d & 511;
    const float invf = powf(10000.f, ((float)(2 * k)) * (-1.f / 1024.f));
    const float a = pos * invf;
    pe[idx] = f2bf((d < 512) ? sinf(a) : cosf(a));
}

// ------------- LayerNorm (fp32 in, bf16 out), one wave per row ----------
__global__ __launch_bounds__(256)
void ln_kernel(const float* __restrict__ inp, const float* __restrict__ gg,
               const float* __restrict__ bb, u16* __restrict__ outp) {
    const int row = blockIdx.x * 4 + (threadIdx.x >> 6);
    const int l = threadIdx.x & 63;
    const size_t base = (size_t)row * 1024 + l * 16;
    float v[16];
    const float4* p4 = (const float4*)(inp + base);
#pragma unroll
    for (int j = 0; j < 4; ++j) {
        float4 f = p4[j];
        v[j*4+0] = f.x; v[j*4+1] = f.y; v[j*4+2] = f.z; v[j*4+3] = f.w;
    }
    float s = 0.f, s2 = 0.f;
#pragma unroll
    for (int j = 0; j < 16; ++j) { s += v[j]; s2 += v[j] * v[j]; }
#pragma unroll
    for (int off = 1; off < 64; off <<= 1) {
        s += __shfl_xor(s, off, 64);
        s2 += __shfl_xor(s2, off, 64);
    }
    const float mu = s * 0.0009765625f;
    const float var = s2 * 0.0009765625f - mu * mu;
    const float rs = rsqrtf(var + 1e-5f);
#pragma unroll
    for (int j = 0; j < 16; ++j)
        outp[base + j] = f2bf((v[j] - mu) * rs * gg[l * 16 + j] + bb[l * 16 + j]);
}

// ---------------- GEMM 128x128 (FF1): proven m97 structure --------------
template<int EPI, bool CATA>
__global__ __launch_bounds__(256)
void gemm_kernel(const u16* __restrict__ A, const u16* __restrict__ A2,
                 const u16* __restrict__ Wt, void* __restrict__ outp,
                 u16* __restrict__ out2, const float* __restrict__ cb1,
                 const float* __restrict__ cb2, const float* __restrict__ residp,
                 int Mdim, int Ndim, int Kdim) {
    __shared__ __attribute__((aligned(16))) u16 As[128 * 32];
    __shared__ __attribute__((aligned(16))) u16 Bs[128 * 32];
    const int tid = threadIdx.x;
    const int w = tid >> 6, l = tid & 63;
    const int wr = w >> 1, wc = w & 1;
    const int m0 = blockIdx.x * 128, n0 = blockIdx.y * 128;
    f32x4 acc[4][4] = {};

    for (int k0 = 0; k0 < Kdim; k0 += 32) {
        __syncthreads();
#pragma unroll
        for (int p = 0; p < 2; ++p) {
            const int ebase = (p * 4 + w) * 512;
            const int e = ebase + l * 8;
            const int row = e >> 5, colk = e & 31;
            const u16* srcA;
            if (CATA) {
                const int rr = m0 + row;
                const int bb_ = rr >> 11, pos = rr & 2047;
                srcA = (pos < 1024 ? A + ((size_t)(bb_ * 1024 + pos)) * 1024
                                   : A2 + ((size_t)(bb_ * 1024 + pos - 1024)) * 1024)
                       + (k0 + colk);
            } else {
                srcA = A + (size_t)(m0 + row) * Kdim + (k0 + colk);
            }
            const u16* srcB = Wt + (size_t)(n0 + row) * Kdim + (k0 + colk);
            GLL16(&As[ebase], srcA);
            GLL16(&Bs[ebase], srcB);
        }
        __syncthreads();
        bf16x8 af[4], bfr[4];
#pragma unroll
        for (int mi = 0; mi < 4; ++mi)
            af[mi] = *(const bf16x8*)&As[(wr * 64 + mi * 16 + (l & 15)) * 32 + (l >> 4) * 8];
#pragma unroll
        for (int ni = 0; ni < 4; ++ni)
            bfr[ni] = *(const bf16x8*)&Bs[(wc * 64 + ni * 16 + (l & 15)) * 32 + (l >> 4) * 8];
#pragma unroll
        for (int mi = 0; mi < 4; ++mi)
#pragma unroll
            for (int ni = 0; ni < 4; ++ni)
                acc[mi][ni] = mfma16(af[mi], bfr[ni], acc[mi][ni]);
    }

#pragma unroll
    for (int mi = 0; mi < 4; ++mi)
#pragma unroll
        for (int ni = 0; ni < 4; ++ni)
#pragma unroll
            for (int rg = 0; rg < 4; ++rg) {
                const int row = m0 + wr * 64 + mi * 16 + (l >> 4) * 4 + rg;
                const int col = n0 + wc * 64 + ni * 16 + (l & 15);
                const size_t idx = (size_t)row * Ndim + col;
                const float v = acc[mi][ni][rg];
                if (EPI == 0) {
                    ((u16*)outp)[idx] = f2bf(v);
                } else if (EPI == 1) {
                    ((u16*)outp)[idx] = f2bf(v + cb1[col]);
                    out2[idx] = f2bf(v + cb2[col]);
                } else if (EPI == 2) {
                    ((float*)outp)[idx] = v + residp[idx];
                } else if (EPI == 3) {
                    const float t = v + cb1[col];
                    ((u16*)outp)[idx] = f2bf(0.5f * t * (1.f + erff(t * 0.70710678118654752f)));
                } else {
                    ((float*)outp)[idx] = v + cb1[col] + residp[idx]; // fp32 y
                }
            }
}

// ---------------- GEMM 64x128 (narrow-N GEMMs): 2x block count ----------
template<int EPI>
__global__ __launch_bounds__(256)
void gemm64_kernel(const u16* __restrict__ A, const u16* __restrict__ Wt,
                   void* __restrict__ outp, u16* __restrict__ out2,
                   const float* __restrict__ cb1, const float* __restrict__ cb2,
                   const float* __restrict__ residp,
                   int Mdim, int Ndim, int Kdim) {
    __shared__ __attribute__((aligned(16))) u16 As[64 * 32];
    __shared__ __attribute__((aligned(16))) u16 Bs[128 * 32];
    const int tid = threadIdx.x;
    const int w = tid >> 6, l = tid & 63;
    const int m0 = blockIdx.x * 64, n0 = blockIdx.y * 128;
    f32x4 acc[4][2] = {};

    for (int k0 = 0; k0 < Kdim; k0 += 32) {
        __syncthreads();
        {
            const int e = (w * 64 + l) * 8;
            const int row = e >> 5, colk = e & 31;
            GLL16(&As[w * 512], A + (size_t)(m0 + row) * Kdim + (k0 + colk));
        }
#pragma unroll
        for (int p = 0; p < 2; ++p) {
            const int ebase = (p * 4 + w) * 512;
            const int e = ebase + l * 8;
            const int row = e >> 5, colk = e & 31;
            GLL16(&Bs[ebase], Wt + (size_t)(n0 + row) * Kdim + (k0 + colk));
        }
        __syncthreads();
        bf16x8 af[4], bfr[2];
#pragma unroll
        for (int mi = 0; mi < 4; ++mi)
            af[mi] = *(const bf16x8*)&As[(mi * 16 + (l & 15)) * 32 + (l >> 4) * 8];
#pragma unroll
        for (int ni = 0; ni < 2; ++ni)
            bfr[ni] = *(const bf16x8*)&Bs[(w * 32 + ni * 16 + (l & 15)) * 32 + (l >> 4) * 8];
#pragma unroll
        for (int mi = 0; mi < 4; ++mi)
#pragma unroll
            for (int ni = 0; ni < 2; ++ni)
                acc[mi][ni] = mfma16(af[mi], bfr[ni], acc[mi][ni]);
    }

#pragma unroll
    for (int mi = 0; mi < 4; ++mi)
#pragma unroll
        for (int ni = 0; ni < 2; ++ni)
#pragma unroll
            for (int rg = 0; rg < 4; ++rg) {
                const int row = m0 + mi * 16 + (l >> 4) * 4 + rg;
                const int col = n0 + w * 32 + ni * 16 + (l & 15);
                const size_t idx = (size_t)row * Ndim + col;
                const float v = acc[mi][ni][rg];
                if (EPI == 0) {
                    ((u16*)outp)[idx] = f2bf(v);
                } else if (EPI == 1) {
                    ((u16*)outp)[idx] = f2bf(v + cb1[col]);
                    out2[idx] = f2bf(v + cb2[col]);
                } else if (EPI == 2) {
                    ((float*)outp)[idx] = v + residp[idx];
                } else {
                    ((float*)outp)[idx] = v + cb1[col] + residp[idx]; // fp32 y
                }
            }
}

// ---------------- fused K+V GEMM: stage A once, compute both ------------
__global__ __launch_bounds__(256)
void gemm_kv_kernel(const u16* __restrict__ A, const u16* __restrict__ A2,
                    const u16* __restrict__ WtK, const u16* __restrict__ WtV,
                    u16* __restrict__ outK, u16* __restrict__ outV) {
    __shared__ __attribute__((aligned(16))) u16 As[128 * 32];
    __shared__ __attribute__((aligned(16))) u16 Bk[128 * 32];
    __shared__ __attribute__((aligned(16))) u16 Bv[128 * 32];
    const int tid = threadIdx.x;
    const int w = tid >> 6, l = tid & 63;
    const int wr = w >> 1, wc = w & 1;
    const int m0 = blockIdx.x * 128, n0 = blockIdx.y * 128;
    f32x4 acck[4][4] = {};
    f32x4 accv[4][4] = {};

    for (int k0 = 0; k0 < 1024; k0 += 32) {
        __syncthreads();
#pragma unroll
        for (int p = 0; p < 2; ++p) {
            const int ebase = (p * 4 + w) * 512;
            const int e = ebase + l * 8;
            const int row = e >> 5, colk = e & 31;
            const int rr = m0 + row;
            const int bb_ = rr >> 11, pos = rr & 2047;
            const u16* srcA = (pos < 1024 ? A + ((size_t)(bb_ * 1024 + pos)) * 1024
                                          : A2 + ((size_t)(bb_ * 1024 + pos - 1024)) * 1024)
                              + (k0 + colk);
            GLL16(&As[ebase], srcA);
            GLL16(&Bk[ebase], WtK + (size_t)(n0 + row) * 1024 + (k0 + colk));
            GLL16(&Bv[ebase], WtV + (size_t)(n0 + row) * 1024 + (k0 + colk));
        }
        __syncthreads();
        bf16x8 af[4], bkf[4], bvf[4];
#pragma unroll
        for (int mi = 0; mi < 4; ++mi)
            af[mi] = *(const bf16x8*)&As[(wr * 64 + mi * 16 + (l & 15)) * 32 + (l >> 4) * 8];
#pragma unroll
        for (int ni = 0; ni < 4; ++ni) {
            const int off = (wc * 64 + ni * 16 + (l & 15)) * 32 + (l >> 4) * 8;
            bkf[ni] = *(const bf16x8*)&Bk[off];
            bvf[ni] = *(const bf16x8*)&Bv[off];
        }
#pragma unroll
        for (int mi = 0; mi < 4; ++mi)
#pragma unroll
            for (int ni = 0; ni < 4; ++ni) {
                acck[mi][ni] = mfma16(af[mi], bkf[ni], acck[mi][ni]);
                accv[mi][ni] = mfma16(af[mi], bvf[ni], accv[mi][ni]);
            }
    }

#pragma unroll
    for (int mi = 0; mi < 4; ++mi)
#pragma unroll
        for (int ni = 0; ni < 4; ++ni)
#pragma unroll
            for (int rg = 0; rg < 4; ++rg) {
                const int row = m0 + wr * 64 + mi * 16 + (l >> 4) * 4 + rg;
                const int col = n0 + wc * 64 + ni * 16 + (l & 15);
                const size_t idx = (size_t)row * 1024 + col;
                outK[idx] = f2bf(acck[mi][ni][rg]);
                outV[idx] = f2bf(accv[mi][ni][rg]);
            }
}

// ---------------- fused rel-attention: software-pipelined staging -------
// Per jt: [A] QK + bands -> mid barrier -> [B] issue next-tile K/Rm/Rw
// GLL16 + V reg-loads -> [C] softmax + PV (covers load latency) ->
// [D] V reg->LDS (buf^1) -> end barrier. K/V double-buffered; R barrier-
// protected. Same 2 barriers/jt as R16.
__global__ __launch_bounds__(256, 2)
void attn_kernel(const u16* __restrict__ qu, const u16* __restrict__ qv,
                 const u16* __restrict__ kcat, const u16* __restrict__ vcat,
                 const u16* __restrict__ rbuf, u16* __restrict__ outp) {
    constexpr int T = 1024, L = 2048, MM = 1024;
    __shared__ __attribute__((aligned(16))) u16 KtL[2][64 * 64];  // 16KB swz
    __shared__ __attribute__((aligned(16))) u16 RmL[128 * 64];    // 16KB swz
    __shared__ __attribute__((aligned(16))) u16 RwL[128 * 64];    // 16KB swz
    __shared__ __attribute__((aligned(16))) u16 Vt[2][64][72];    // 18KB (j')
    __shared__ __attribute__((aligned(16))) u16 Pl[4][16][72];    // 9KB (j')
    const int bid = blockIdx.x;
    const int g = (bid & 7) + 8 * (bid >> 7);   // head-group (XCD swizzle)
    const int it = (bid >> 3) & 15;
    const int h = g & 15, b = g >> 4;
    const int i0 = it * 64;
    const int tid = threadIdx.x;
    const int w = tid >> 6, l = tid & 63;
    const int lg = l >> 4, ll = l & 15;
    const int iw0 = i0 + w * 16;
    const int l8 = l >> 3;
    const int ssrc = ((l & 7) * 8) ^ (l8 << 3);
    const int sA = (lg * 8) ^ ((ll & 7) << 3);
    const int sB = (lg * 8 + 32) ^ ((ll & 7) << 3);

    bf16x8 quf[2], qvf[2];
    const int qc = h * 64 + lg * 8;
    {
        const size_t qrow = (size_t)(b * T + iw0 + ll);
        quf[0] = *(const bf16x8*)&qu[qrow * 1024 + qc];
        quf[1] = *(const bf16x8*)&qu[qrow * 1024 + qc + 32];
        qvf[0] = *(const bf16x8*)&qv[qrow * 1024 + qc];
        qvf[1] = *(const bf16x8*)&qv[qrow * 1024 + qc + 32];
    }
    const int r2 = iw0 + ll + 1;
    const size_t qrow2 = (size_t)(b * T + (r2 < T ? r2 : T - 1));
    const u16* kb = kcat + (size_t)b * L * 1024 + h * 64;
    const u16* vb = vcat + (size_t)b * L * 1024 + h * 64;
    const u16* rb = rbuf + h * 64;

    f32x4 o_acc[4] = {};
    f32x4 o_sum = {0.f, 0.f, 0.f, 0.f};
    float m_run[4] = {-1e30f, -1e30f, -1e30f, -1e30f};
    const bf16x8 onesb = {(short)0x3F80, (short)0x3F80, (short)0x3F80, (short)0x3F80,
                          (short)0x3F80, (short)0x3F80, (short)0x3F80, (short)0x3F80};
    const int vjq = tid & 15, vdg = tid >> 4;

    // ---- prologue: stage jt=0 (main band always active at jt=0) ----
#pragma unroll
    for (int p = 0; p < 2; ++p) {
        const int k8 = w * 2 + p;
        GLL16(&KtL[0][k8 * 512], kb + (size_t)(k8 * 8 + l8) * 1024 + ssrc);
    }
    {
        const long bm = (long)T - i0 - 64;
#pragma unroll
        for (int p = 0; p < 4; ++p) {
            const int k8 = w * 4 + p;
            GLL16(&RmL[k8 * 512], rb + (long)(bm + k8 * 8 + l8) * 1024 + ssrc);
        }
        const u16* srcv = vb + (size_t)vjq * 1024 + vdg * 4;
        const ushort4 r0 = *(const ushort4*)(srcv);
        const ushort4 r1 = *(const ushort4*)(srcv + 16 * 1024);
        const ushort4 r2w = *(const ushort4*)(srcv + 32 * 1024);
        const ushort4 r3 = *(const ushort4*)(srcv + 48 * 1024);
        *(ushort4*)&Vt[0][vdg * 4 + 0][vjq * 4] = (ushort4){r0.x, r1.x, r2w.x, r3.x};
        *(ushort4*)&Vt[0][vdg * 4 + 1][vjq * 4] = (ushort4){r0.y, r1.y, r2w.y, r3.y};
        *(ushort4*)&Vt[0][vdg * 4 + 2][vjq * 4] = (ushort4){r0.z, r1.z, r2w.z, r3.z};
        *(ushort4*)&Vt[0][vdg * 4 + 3][vjq * 4] = (ushort4){r0.w, r1.w, r2w.w, r3.w};
    }
    __syncthreads();

    for (int jt = 0; jt < 32; ++jt) {
        const int j0 = jt * 64;
        const int buf = jt & 1;
        const bool main_blk = (j0 <= MM + i0 + 63);
        const bool wrap_blk = (j0 + 63 >= MM + i0 + 2);

        // ---- [A] content scores + bands (reads K[buf], RmL, RwL) ----
        f32x4 sv[4];
        __builtin_amdgcn_s_setprio(1);
#pragma unroll
        for (int ns = 0; ns < 4; ++ns) {
            const int rowb = (ns * 16 + ll) * 64;
            f32x4 a = {0.f, 0.f, 0.f, 0.f};
            a = mfma16(quf[0], *(const bf16x8*)&KtL[buf][rowb + sA], a);
            a = mfma16(quf[1], *(const bf16x8*)&KtL[buf][rowb + sB], a);
            sv[ns] = a;
        }
        __builtin_amdgcn_s_setprio(0);

        if (main_blk && j0 <= MM + iw0 + 15) {
            const int trb = 48 - 16 * w;
            f32x4 gb[5];
#pragma unroll
            for (int cs = 0; cs < 5; ++cs) {
                const int rowb = (trb + cs * 16 + ll) * 64;
                f32x4 a = {0.f, 0.f, 0.f, 0.f};
                a = mfma16(qvf[0], *(const bf16x8*)&RmL[rowb + sA], a);
                a = mfma16(qvf[1], *(const bf16x8*)&RmL[rowb + sB], a);
                gb[cs] = a;
            }
#pragma unroll
            for (int r = 0; r < 4; ++r) {
                const int i_loc = lg * 4 + r;
                const int srcl = (l & 48) | ((ll + 15 - i_loc) & 15);
                const float sh0 = __shfl(gb[0][r], srcl, 64);
                const float sh1 = __shfl(gb[1][r], srcl, 64);
                const float sh2 = __shfl(gb[2][r], srcl, 64);
                const float sh3 = __shfl(gb[3][r], srcl, 64);
                const float sh4 = __shfl(gb[4][r], srcl, 64);
                const bool hi = (ll > i_loc);
                const int thr = MM + iw0 + i_loc - j0;
                const float e0 = hi ? sh1 : sh0;
                const float e1 = hi ? sh2 : sh1;
                const float e2 = hi ? sh3 : sh2;
                const float e3 = hi ? sh4 : sh3;
                if (ll <= thr)      sv[0][r] += e0;
                if (16 + ll <= thr) sv[1][r] += e1;
                if (32 + ll <= thr) sv[2][r] += e2;
                if (48 + ll <= thr) sv[3][r] += e3;
            }
        }
        if (wrap_blk && j0 + 63 >= MM + iw0 + 2) {
            const bf16x8 qv2f0 = *(const bf16x8*)&qv[qrow2 * 1024 + qc];
            const bf16x8 qv2f1 = *(const bf16x8*)&qv[qrow2 * 1024 + qc + 32];
            const int trb = 48 - 16 * w;
            f32x4 gb[5];
#pragma unroll
            for (int cs = 0; cs < 5; ++cs) {
                const int rowb = (trb + cs * 16 + ll) * 64;
                f32x4 a = {0.f, 0.f, 0.f, 0.f};
                a = mfma16(qv2f0, *(const bf16x8*)&RwL[rowb + sA], a);
                a = mfma16(qv2f1, *(const bf16x8*)&RwL[rowb + sB], a);
                gb[cs] = a;
            }
#pragma unroll
            for (int r = 0; r < 4; ++r) {
                const int i_loc = lg * 4 + r;
                const int srcl = (l & 48) | ((ll + 15 - i_loc) & 15);
                const float sh0 = __shfl(gb[0][r], srcl, 64);
                const float sh1 = __shfl(gb[1][r], srcl, 64);
                const float sh2 = __shfl(gb[2][r], srcl, 64);
                const float sh3 = __shfl(gb[3][r], srcl, 64);
                const float sh4 = __shfl(gb[4][r], srcl, 64);
                const bool hi = (ll > i_loc);
                const int thr2 = MM + iw0 + i_loc - j0 + 2;
                const float e0 = hi ? sh1 : sh0;
                const float e1 = hi ? sh2 : sh1;
                const float e2 = hi ? sh3 : sh2;
                const float e3 = hi ? sh4 : sh3;
                if (ll >= thr2)      sv[0][r] += e0;
                if (16 + ll >= thr2) sv[1][r] += e1;
                if (32 + ll >= thr2) sv[2][r] += e2;
                if (48 + ll >= thr2) sv[3][r] += e3;
            }
        }
        __syncthreads();   // mid barrier: all waves done reading RmL/RwL/K[buf]

        // ---- [B] issue next-tile stages (latency covered by [C]) ----
        ushort4 vr0, vr1, vr2, vr3;
        if (jt < 31) {
            const int j1 = j0 + 64;
#pragma unroll
            for (int p = 0; p < 2; ++p) {
                const int k8 = w * 2 + p;
                GLL16(&KtL[buf ^ 1][k8 * 512], kb + (size_t)(j1 + k8 * 8 + l8) * 1024 + ssrc);
            }
            if (j1 <= MM + i0 + 63) {
                const long bm = (long)j1 + T - i0 - 64;
#pragma unroll
                for (int p = 0; p < 4; ++p) {
                    const int k8 = w * 4 + p;
                    GLL16(&RmL[k8 * 512], rb + (long)(bm + k8 * 8 + l8) * 1024 + ssrc);
                }
            }
            if (j1 + 63 >= MM + i0 + 2) {
                const long bw_ = (long)j1 - MM - i0 - 65;
#pragma unroll
                for (int p = 0; p < 4; ++p) {
                    const int k8 = w * 4 + p;
                    GLL16(&RwL[k8 * 512], rb + (long)(bw_ + k8 * 8 + l8) * 1024 + ssrc);
                }
            }
            const u16* srcv = vb + (size_t)(j1 + vjq) * 1024 + vdg * 4;
            vr0 = *(const ushort4*)(srcv);
            vr1 = *(const ushort4*)(srcv + 16 * 1024);
            vr2 = *(const ushort4*)(srcv + 32 * 1024);
            vr3 = *(const ushort4*)(srcv + 48 * 1024);
        }

        // ---- [C] online softmax + packed P ----
#pragma unroll
        for (int r = 0; r < 4; ++r) {
            const int i_loc = lg * 4 + r;
            const float s0 = sv[0][r] * 0.125f, s1 = sv[1][r] * 0.125f;
            const float s2 = sv[2][r] * 0.125f, s3 = sv[3][r] * 0.125f;
            float pm = fmaxf(fmaxf(s0, s1), fmaxf(s2, s3));
            pm = fmaxf(pm, __shfl_xor(pm, 1, 64));
            pm = fmaxf(pm, __shfl_xor(pm, 2, 64));
            pm = fmaxf(pm, __shfl_xor(pm, 4, 64));
            pm = fmaxf(pm, __shfl_xor(pm, 8, 64));
            const float mnew = fmaxf(m_run[r], pm);
            const float alpha = __expf(m_run[r] - mnew);
            const float p0 = __expf(s0 - mnew), p1 = __expf(s1 - mnew);
            const float p2 = __expf(s2 - mnew), p3 = __expf(s3 - mnew);
            const ushort4 pw = {f2bf(p0), f2bf(p1), f2bf(p2), f2bf(p3)};
            *(ushort4*)&Pl[w][i_loc][ll * 4] = pw;
            m_run[r] = mnew;
            o_sum[r] *= alpha;
#pragma unroll
            for (int ns = 0; ns < 4; ++ns) o_acc[ns][r] *= alpha;
        }

        // ---- PV from V[buf] (j'-order); denominators via ones-B ----
        __builtin_amdgcn_s_setprio(1);
        const bf16x8 ap0 = *(const bf16x8*)&Pl[w][ll][lg * 8];
        const bf16x8 ap1 = *(const bf16x8*)&Pl[w][ll][32 + lg * 8];
#pragma unroll
        for (int ns = 0; ns < 4; ++ns) {
            const bf16x8 bv0 = *(const bf16x8*)&Vt[buf][ns * 16 + ll][lg * 8];
            const bf16x8 bv1 = *(const bf16x8*)&Vt[buf][ns * 16 + ll][32 + lg * 8];
            o_acc[ns] = mfma16(ap0, bv0, o_acc[ns]);
            o_acc[ns] = mfma16(ap1, bv1, o_acc[ns]);
        }
        o_sum = mfma16(ap0, onesb, o_sum);
        o_sum = mfma16(ap1, onesb, o_sum);
        __builtin_amdgcn_s_setprio(0);

        // ---- [D] write next-tile V regs into Vt[buf^1] ----
        if (jt < 31) {
            *(ushort4*)&Vt[buf ^ 1][vdg * 4 + 0][vjq * 4] = (ushort4){vr0.x, vr1.x, vr2.x, vr3.x};
            *(ushort4*)&Vt[buf ^ 1][vdg * 4 + 1][vjq * 4] = (ushort4){vr0.y, vr1.y, vr2.y, vr3.y};
            *(ushort4*)&Vt[buf ^ 1][vdg * 4 + 2][vjq * 4] = (ushort4){vr0.z, vr1.z, vr2.z, vr3.z};
            *(ushort4*)&Vt[buf ^ 1][vdg * 4 + 3][vjq * 4] = (ushort4){vr0.w, vr1.w, vr2.w, vr3.w};
        }
        __syncthreads();   // end barrier: drains GLL16s + V ds_writes
    }

#pragma unroll
    for (int ns = 0; ns < 4; ++ns)
#pragma unroll
        for (int r = 0; r < 4; ++r) {
            const int row = iw0 + lg * 4 + r;
            outp[(size_t)(b * T + row) * 1024 + h * 64 + ns * 16 + ll] =
                f2bf(o_acc[ns][r] / o_sum[r]);
        }
}

// ------------------------------- launch ---------------------------------
extern "C" void kernel_launch(void* const* d_in, const int* in_sizes, int n_in,
                              void* d_out, int out_size, void* d_ws, size_t ws_size,
                              hipStream_t stream) {
    const float* x    = (const float*)d_in[0];
    const float* mem  = (const float*)d_in[1];
    const float* Wq   = (const float*)d_in[2];
    const float* Wk   = (const float*)d_in[3];
    const float* Wv   = (const float*)d_in[4];
    const float* Wr   = (const float*)d_in[5];
    const float* Wo   = (const float*)d_in[6];
    const float* bu   = (const float*)d_in[7];
    const float* bv   = (const float*)d_in[8];
    const float* ln1g = (const float*)d_in[9];
    const float* ln1b = (const float*)d_in[10];
    const float* ln2g = (const float*)d_in[11];
    const float* ln2b = (const float*)d_in[12];
    const float* W1   = (const float*)d_in[13];
    const float* b1   = (const float*)d_in[14];
    const float* W2   = (const float*)d_in[15];
    const float* b2   = (const float*)d_in[16];

    float* y_out   = (float*)d_out;
    float* mem_out = (float*)d_out + 4194304;

    // ===== d_out (32 MB fp32) as scratch, time-multiplexed =====
    char* dob = (char*)d_out;
    u16* attno     = (u16*)(dob + 0);
    u16* pe        = (u16*)(dob + (size_t)8  * 1048576);
    u16* rbuf_base = (u16*)(dob + (size_t)12 * 1048576);
    u16* rbuf      = rbuf_base + 80 * 1024;           // padded +/-80 rows
    char* dw = dob + (size_t)16 * 1048576 + 524288;   // 16.5 MB
    u16* WqT = (u16*)(dw);
    u16* WkT = (u16*)(dw + (size_t)2 * 1048576);
    u16* WvT = (u16*)(dw + (size_t)4 * 1048576);
    u16* WrT = (u16*)(dw + (size_t)6 * 1048576);
    u16* WoT = (u16*)(dw + (size_t)8 * 1048576);

    // ===== ws layout, extent 64 MB =====
    char* ws = (char*)d_ws;
    const size_t MB = 1u << 20;
    u16*  xn    = (u16*)(ws + 0 * MB);
    u16*  x2n   = (u16*)(ws + 0 * MB);
    u16*  W2T   = (u16*)(ws + 0 * MB);
    u16*  qu    = (u16*)(ws + 8 * MB);
    float* x2f  = (float*)(ws + 8 * MB);
    u16*  qv    = (u16*)(ws + 16 * MB);
    u16*  kcat  = (u16*)(ws + 24 * MB);
    u16*  ffh   = (u16*)(ws + 24 * MB);
    u16*  vcat  = (u16*)(ws + 40 * MB);
    u16*  memb  = (u16*)(ws + 56 * MB);
    u16*  W1T   = (u16*)(ws + 56 * MB);

    transpose5_kernel<<<dim3(32, 32, 5), 256, 0, stream>>>(Wq, Wk, Wv, Wr, Wo,
                                                           WqT, WkT, WvT, WrT, WoT);
    pe_kernel<<<8192, 256, 0, stream>>>(pe);
    convert_kernel<<<2048, 256, 0, stream>>>(mem, memb);
    ln_kernel<<<1024, 256, 0, stream>>>(x, ln1g, ln1b, xn);
    gemm64_kernel<0><<<dim3(32, 8), 256, 0, stream>>>(pe, WrT, rbuf, nullptr, nullptr, nullptr, nullptr, 2048, 1024, 1024);
    gemm64_kernel<1><<<dim3(64, 8), 256, 0, stream>>>(xn, WqT, qu, qv, bu, bv, nullptr, 4096, 1024, 1024);
    gemm_kv_kernel<<<dim3(64, 8), 256, 0, stream>>>(memb, xn, WkT, WvT, kcat, vcat);
    attn_kernel<<<1024, 256, 0, stream>>>(qu, qv, kcat, vcat, rbuf, attno);
    gemm64_kernel<2><<<dim3(64, 8), 256, 0, stream>>>(attno, WoT, x2f, nullptr, nullptr, nullptr, x, 4096, 1024, 1024);
    transpose_kernel<<<dim3(128, 32), 256, 0, stream>>>(W1, W1T, 1024, 4096);
    hipMemcpyAsync(mem_out, x, (size_t)4194304 * 4, hipMemcpyDeviceToDevice, stream);
    ln_kernel<<<1024, 256, 0, stream>>>(x2f, ln2g, ln2b, x2n);
    gemm_kernel<3, false><<<dim3(32, 32), 256, 0, stream>>>(x2n, nullptr, W1T, ffh, nullptr, b1, nullptr, nullptr, 4096, 4096, 1024);
    transpose_kernel<<<dim3(32, 128), 256, 0, stream>>>(W2, W2T, 4096, 1024);
    gemm64_kernel<4><<<dim3(64, 8), 256, 0, stream>>>(ffh, W2T, y_out, nullptr, b2, nullptr, x2f, 4096, 1024, 4096);
    (void)in_sizes; (void)n_in; (void)out_size; (void)ws_size;
}

// Round 19
// 493.706 us; speedup vs baseline: 1.1188x; 1.0930x over previous
//
#include <hip/hip_runtime.h>
#include <hip/hip_bf16.h>

typedef short bf16x8 __attribute__((ext_vector_type(8)));
typedef float f32x4 __attribute__((ext_vector_type(4)));
typedef unsigned short u16;

__device__ __forceinline__ float bf2f(u16 u) {
    union { unsigned int i; float f; } x; x.i = ((unsigned int)u) << 16; return x.f;
}
__device__ __forceinline__ u16 f2bf(float f) {
    union { float f; unsigned int i; } x; x.f = f;
    unsigned int r = x.i + 0x7fff + ((x.i >> 16) & 1);
    return (u16)(r >> 16);
}
__device__ __forceinline__ f32x4 mfma16(bf16x8 a, bf16x8 b, f32x4 c) {
    return __builtin_amdgcn_mfma_f32_16x16x32_bf16(a, b, c, 0, 0, 0);
}
#define GLL16(lds_base, gsrc) \
    __builtin_amdgcn_global_load_lds((const __attribute__((address_space(1))) void*)(gsrc), \
                                     (__attribute__((address_space(3))) void*)(lds_base), 16, 0, 0)

// ------------- fused transpose of five 1024x1024 weights ----------------
__global__ __launch_bounds__(256)
void transpose5_kernel(const float* __restrict__ s0, const float* __restrict__ s1,
                       const float* __restrict__ s2, const float* __restrict__ s3,
                       const float* __restrict__ s4,
                       u16* __restrict__ d0, u16* __restrict__ d1,
                       u16* __restrict__ d2, u16* __restrict__ d3,
                       u16* __restrict__ d4) {
    const float* in; u16* out;
    switch (blockIdx.z) {
        case 0: in = s0; out = d0; break;
        case 1: in = s1; out = d1; break;
        case 2: in = s2; out = d2; break;
        case 3: in = s3; out = d3; break;
        default: in = s4; out = d4; break;
    }
    __shared__ float t[32][33];
    const int c0 = blockIdx.x * 32, r0 = blockIdx.y * 32;
    const int tx = threadIdx.x & 31, ty = threadIdx.x >> 5;
#pragma unroll
    for (int i = 0; i < 32; i += 8) t[ty + i][tx] = in[(size_t)(r0 + ty + i) * 1024 + c0 + tx];
    __syncthreads();
#pragma unroll
    for (int i = 0; i < 32; i += 8) out[(size_t)(c0 + ty + i) * 1024 + r0 + tx] = f2bf(t[tx][ty + i]);
}

// ------------- transpose fp32 [R][C] -> bf16 [C][R] ---------------------
__global__ __launch_bounds__(256)
void transpose_kernel(const float* __restrict__ in, u16* __restrict__ out, int R, int C) {
    __shared__ float t[32][33];
    const int c0 = blockIdx.x * 32, r0 = blockIdx.y * 32;
    const int tx = threadIdx.x & 31, ty = threadIdx.x >> 5;
#pragma unroll
    for (int i = 0; i < 32; i += 8) t[ty + i][tx] = in[(size_t)(r0 + ty + i) * C + c0 + tx];
    __syncthreads();
#pragma unroll
    for (int i = 0; i < 32; i += 8) out[(size_t)(c0 + ty + i) * R + r0 + tx] = f2bf(t[tx][ty + i]);
}

// ------------- fp32 -> bf16 convert (8 elems/thread) --------------------
__global__ __launch_bounds__(256)
void convert_kernel(const float* __restrict__ in, u16* __restrict__ out) {
    const size_t i = ((size_t)blockIdx.x * 256 + threadIdx.x) * 8;
    const float4 a = *(const float4*)(in + i);
    const float4 b = *(const float4*)(in + i + 4);
    bf16x8 o;
    o[0] = (short)f2bf(a.x); o[1] = (short)f2bf(a.y);
    o[2] = (short)f2bf(a.z); o[3] = (short)f2bf(a.w);
    o[4] = (short)f2bf(b.x); o[5] = (short)f2bf(b.y);
    o[6] = (short)f2bf(b.z); o[7] = (short)f2bf(b.w);
    *(bf16x8*)(out + i) = o;
}

// ------------- positional embedding pe[2048][1024] (bf16) ---------------
__global__ __launch_bounds__(256)
void pe_kernel(u16* __restrict__ pe) {
    const int idx = blockIdx.x * 256 + threadIdx.x;
    const int p = idx >> 10, d = idx & 1023;
    const float pos = (float)(2047 - p);
    const int k = d & 511;
    const float invf = powf(10000.f, ((float)(2 * k)) * (-1.f / 1024.f));
    const float a = pos * invf;
    pe[idx] = f2bf((d < 512) ? sinf(a) : cosf(a));
}

// ------------- LayerNorm (fp32 in, bf16 out), one wave per row ----------
__global__ __launch_bounds__(256)
void ln_kernel(const float* __restrict__ inp, const float* __restrict__ gg,
               const float* __restrict__ bb, u16* __restrict__ outp) {
    const int row = blockIdx.x * 4 + (threadIdx.x >> 6);
    const int l = threadIdx.x & 63;
    const size_t base = (size_t)row * 1024 + l * 16;
    float v[16];
    const float4* p4 = (const float4*)(inp + base);
#pragma unroll
    for (int j = 0; j < 4; ++j) {
        float4 f = p4[j];
        v[j*4+0] = f.x; v[j*4+1] = f.y; v[j*4+2] = f.z; v[j*4+3] = f.w;
    }
    float s = 0.f, s2 = 0.f;
#pragma unroll
    for (int j = 0; j < 16; ++j) { s += v[j]; s2 += v[j] * v[j]; }
#pragma unroll
    for (int off = 1; off < 64; off <<= 1) {
        s += __shfl_xor(s, off, 64);
        s2 += __shfl_xor(s2, off, 64);
    }
    const float mu = s * 0.0009765625f;
    const float var = s2 * 0.0009765625f - mu * mu;
    const float rs = rsqrtf(var + 1e-5f);
#pragma unroll
    for (int j = 0; j < 16; ++j)
        outp[base + j] = f2bf((v[j] - mu) * rs * gg[l * 16 + j] + bb[l * 16 + j]);
}

// ---------------- GEMM 128x128 (FF1): proven m97 structure --------------
template<int EPI, bool CATA>
__global__ __launch_bounds__(256)
void gemm_kernel(const u16* __restrict__ A, const u16* __restrict__ A2,
                 const u16* __restrict__ Wt, void* __restrict__ outp,
                 u16* __restrict__ out2, const float* __restrict__ cb1,
                 const float* __restrict__ cb2, const float* __restrict__ residp,
                 int Mdim, int Ndim, int Kdim) {
    __shared__ __attribute__((aligned(16))) u16 As[128 * 32];
    __shared__ __attribute__((aligned(16))) u16 Bs[128 * 32];
    const int tid = threadIdx.x;
    const int w = tid >> 6, l = tid & 63;
    const int wr = w >> 1, wc = w & 1;
    const int m0 = blockIdx.x * 128, n0 = blockIdx.y * 128;
    f32x4 acc[4][4] = {};

    for (int k0 = 0; k0 < Kdim; k0 += 32) {
        __syncthreads();
#pragma unroll
        for (int p = 0; p < 2; ++p) {
            const int ebase = (p * 4 + w) * 512;
            const int e = ebase + l * 8;
            const int row = e >> 5, colk = e & 31;
            const u16* srcA;
            if (CATA) {
                const int rr = m0 + row;
                const int bb_ = rr >> 11, pos = rr & 2047;
                srcA = (pos < 1024 ? A + ((size_t)(bb_ * 1024 + pos)) * 1024
                                   : A2 + ((size_t)(bb_ * 1024 + pos - 1024)) * 1024)
                       + (k0 + colk);
            } else {
                srcA = A + (size_t)(m0 + row) * Kdim + (k0 + colk);
            }
            const u16* srcB = Wt + (size_t)(n0 + row) * Kdim + (k0 + colk);
            GLL16(&As[ebase], srcA);
            GLL16(&Bs[ebase], srcB);
        }
        __syncthreads();
        bf16x8 af[4], bfr[4];
#pragma unroll
        for (int mi = 0; mi < 4; ++mi)
            af[mi] = *(const bf16x8*)&As[(wr * 64 + mi * 16 + (l & 15)) * 32 + (l >> 4) * 8];
#pragma unroll
        for (int ni = 0; ni < 4; ++ni)
            bfr[ni] = *(const bf16x8*)&Bs[(wc * 64 + ni * 16 + (l & 15)) * 32 + (l >> 4) * 8];
#pragma unroll
        for (int mi = 0; mi < 4; ++mi)
#pragma unroll
            for (int ni = 0; ni < 4; ++ni)
                acc[mi][ni] = mfma16(af[mi], bfr[ni], acc[mi][ni]);
    }

#pragma unroll
    for (int mi = 0; mi < 4; ++mi)
#pragma unroll
        for (int ni = 0; ni < 4; ++ni)
#pragma unroll
            for (int rg = 0; rg < 4; ++rg) {
                const int row = m0 + wr * 64 + mi * 16 + (l >> 4) * 4 + rg;
                const int col = n0 + wc * 64 + ni * 16 + (l & 15);
                const size_t idx = (size_t)row * Ndim + col;
                const float v = acc[mi][ni][rg];
                if (EPI == 0) {
                    ((u16*)outp)[idx] = f2bf(v);
                } else if (EPI == 1) {
                    ((u16*)outp)[idx] = f2bf(v + cb1[col]);
                    out2[idx] = f2bf(v + cb2[col]);
                } else if (EPI == 2) {
                    ((float*)outp)[idx] = v + residp[idx];
                } else if (EPI == 3) {
                    const float t = v + cb1[col];
                    ((u16*)outp)[idx] = f2bf(0.5f * t * (1.f + erff(t * 0.70710678118654752f)));
                } else {
                    ((float*)outp)[idx] = v + cb1[col] + residp[idx]; // fp32 y
                }
            }
}

// ---------------- GEMM 64x128, BK=64, XOR-swizzled LDS ------------------
// 16 MFMA per barrier round (vs 8 at BK=32); staging pattern identical to
// the attn K-tile (verified involution: src col ((l&7)*8)^(l8<<3), read
// col ((kk*4+lg)*8)^((ll&7)<<3)).
template<int EPI>
__global__ __launch_bounds__(256)
void gemm64_kernel(const u16* __restrict__ A, const u16* __restrict__ Wt,
                   void* __restrict__ outp, u16* __restrict__ out2,
                   const float* __restrict__ cb1, const float* __restrict__ cb2,
                   const float* __restrict__ residp,
                   int Mdim, int Ndim, int Kdim) {
    __shared__ __attribute__((aligned(16))) u16 As[64 * 64];    // 8KB swz
    __shared__ __attribute__((aligned(16))) u16 Bs[128 * 64];   // 16KB swz
    const int tid = threadIdx.x;
    const int w = tid >> 6, l = tid & 63;
    const int lg = l >> 4, ll = l & 15;
    const int l8 = l >> 3;
    const int ssrc = ((l & 7) * 8) ^ (l8 << 3);
    const int m0 = blockIdx.x * 64, n0 = blockIdx.y * 128;
    f32x4 acc[4][2] = {};

    for (int k0 = 0; k0 < Kdim; k0 += 64) {
        __syncthreads();
#pragma unroll
        for (int p = 0; p < 2; ++p) {   // A rows 0..63
            const int k8 = w * 2 + p;
            GLL16(&As[k8 * 512], A + (size_t)(m0 + k8 * 8 + l8) * Kdim + k0 + ssrc);
        }
#pragma unroll
        for (int p = 0; p < 4; ++p) {   // B rows 0..127
            const int k8 = w * 4 + p;
            GLL16(&Bs[k8 * 512], Wt + (size_t)(n0 + k8 * 8 + l8) * Kdim + k0 + ssrc);
        }
        __syncthreads();
#pragma unroll
        for (int kk = 0; kk < 2; ++kk) {
            const int cA = ((kk * 4 + lg) * 8) ^ ((ll & 7) << 3);
            bf16x8 af[4], bfr[2];
#pragma unroll
            for (int mi = 0; mi < 4; ++mi)
                af[mi] = *(const bf16x8*)&As[(mi * 16 + ll) * 64 + cA];
#pragma unroll
            for (int ni = 0; ni < 2; ++ni)
                bfr[ni] = *(const bf16x8*)&Bs[(w * 32 + ni * 16 + ll) * 64 + cA];
#pragma unroll
            for (int mi = 0; mi < 4; ++mi)
#pragma unroll
                for (int ni = 0; ni < 2; ++ni)
                    acc[mi][ni] = mfma16(af[mi], bfr[ni], acc[mi][ni]);
        }
    }

#pragma unroll
    for (int mi = 0; mi < 4; ++mi)
#pragma unroll
        for (int ni = 0; ni < 2; ++ni)
#pragma unroll
            for (int rg = 0; rg < 4; ++rg) {
                const int row = m0 + mi * 16 + lg * 4 + rg;
                const int col = n0 + w * 32 + ni * 16 + ll;
                const size_t idx = (size_t)row * Ndim + col;
                const float v = acc[mi][ni][rg];
                if (EPI == 0) {
                    ((u16*)outp)[idx] = f2bf(v);
                } else if (EPI == 1) {
                    ((u16*)outp)[idx] = f2bf(v + cb1[col]);
                    out2[idx] = f2bf(v + cb2[col]);
                } else if (EPI == 2) {
                    ((float*)outp)[idx] = v + residp[idx];
                } else {
                    ((float*)outp)[idx] = v + cb1[col] + residp[idx]; // fp32 y
                }
            }
}

// ---------------- fused K+V GEMM: BK=64, swizzled, A staged once --------
__global__ __launch_bounds__(256)
void gemm_kv_kernel(const u16* __restrict__ A, const u16* __restrict__ A2,
                    const u16* __restrict__ WtK, const u16* __restrict__ WtV,
                    u16* __restrict__ outK, u16* __restrict__ outV) {
    __shared__ __attribute__((aligned(16))) u16 As[128 * 64];   // 16KB swz
    __shared__ __attribute__((aligned(16))) u16 Bk[128 * 64];   // 16KB swz
    __shared__ __attribute__((aligned(16))) u16 Bv[128 * 64];   // 16KB swz
    const int tid = threadIdx.x;
    const int w = tid >> 6, l = tid & 63;
    const int lg = l >> 4, ll = l & 15;
    const int wr = w >> 1, wc = w & 1;
    const int l8 = l >> 3;
    const int ssrc = ((l & 7) * 8) ^ (l8 << 3);
    const int m0 = blockIdx.x * 128, n0 = blockIdx.y * 128;
    f32x4 acck[4][4] = {};
    f32x4 accv[4][4] = {};

    for (int k0 = 0; k0 < 1024; k0 += 64) {
        __syncthreads();
#pragma unroll
        for (int p = 0; p < 4; ++p) {
            const int k8 = w * 4 + p;
            const int rr = m0 + k8 * 8 + l8;
            const int bb_ = rr >> 11, pos = rr & 2047;
            const u16* srcA = (pos < 1024 ? A + ((size_t)(bb_ * 1024 + pos)) * 1024
                                          : A2 + ((size_t)(bb_ * 1024 + pos - 1024)) * 1024)
                              + k0 + ssrc;
            GLL16(&As[k8 * 512], srcA);
            GLL16(&Bk[k8 * 512], WtK + (size_t)(n0 + k8 * 8 + l8) * 1024 + k0 + ssrc);
            GLL16(&Bv[k8 * 512], WtV + (size_t)(n0 + k8 * 8 + l8) * 1024 + k0 + ssrc);
        }
        __syncthreads();
#pragma unroll
        for (int kk = 0; kk < 2; ++kk) {
            const int cA = ((kk * 4 + lg) * 8) ^ ((ll & 7) << 3);
            bf16x8 af[4], bkf[4], bvf[4];
#pragma unroll
            for (int mi = 0; mi < 4; ++mi)
                af[mi] = *(const bf16x8*)&As[(wr * 64 + mi * 16 + ll) * 64 + cA];
#pragma unroll
            for (int ni = 0; ni < 4; ++ni) {
                const int off = (wc * 64 + ni * 16 + ll) * 64 + cA;
                bkf[ni] = *(const bf16x8*)&Bk[off];
                bvf[ni] = *(const bf16x8*)&Bv[off];
            }
#pragma unroll
            for (int mi = 0; mi < 4; ++mi)
#pragma unroll
                for (int ni = 0; ni < 4; ++ni) {
                    acck[mi][ni] = mfma16(af[mi], bkf[ni], acck[mi][ni]);
                    accv[mi][ni] = mfma16(af[mi], bvf[ni], accv[mi][ni]);
                }
        }
    }

#pragma unroll
    for (int mi = 0; mi < 4; ++mi)
#pragma unroll
        for (int ni = 0; ni < 4; ++ni)
#pragma unroll
            for (int rg = 0; rg < 4; ++rg) {
                const int row = m0 + wr * 64 + mi * 16 + lg * 4 + rg;
                const int col = n0 + wc * 64 + ni * 16 + ll;
                const size_t idx = (size_t)row * 1024 + col;
                outK[idx] = f2bf(acck[mi][ni][rg]);
                outV[idx] = f2bf(accv[mi][ni][rg]);
            }
}

// ---------------- fused rel-attention (R16 best: j-perm P/V, ones-sum) --
__global__ __launch_bounds__(256, 2)
void attn_kernel(const u16* __restrict__ qu, const u16* __restrict__ qv,
                 const u16* __restrict__ kcat, const u16* __restrict__ vcat,
                 const u16* __restrict__ rbuf, u16* __restrict__ outp) {
    constexpr int T = 1024, L = 2048, MM = 1024;
    __shared__ __attribute__((aligned(16))) u16 KtL[64 * 64];   // 8KB swz
    __shared__ __attribute__((aligned(16))) u16 RmL[128 * 64];  // 16KB swz
    __shared__ __attribute__((aligned(16))) u16 RwL[128 * 64];  // 16KB swz
    __shared__ __attribute__((aligned(16))) u16 Vt[64][72];     // 9KB (j')
    __shared__ __attribute__((aligned(16))) u16 Pl[4][16][72];  // 9KB (j')
    const int bid = blockIdx.x;
    const int g = (bid & 7) + 8 * (bid >> 7);   // head-group (XCD swizzle)
    const int it = (bid >> 3) & 15;
    const int h = g & 15, b = g >> 4;
    const int i0 = it * 64;
    const int tid = threadIdx.x;
    const int w = tid >> 6, l = tid & 63;
    const int lg = l >> 4, ll = l & 15;
    const int iw0 = i0 + w * 16;
    const int l8 = l >> 3;
    const int ssrc = ((l & 7) * 8) ^ (l8 << 3);
    const int sA = (lg * 8) ^ ((ll & 7) << 3);
    const int sB = (lg * 8 + 32) ^ ((ll & 7) << 3);

    bf16x8 quf[2], qvf[2];
    const int qc = h * 64 + lg * 8;
    {
        const size_t qrow = (size_t)(b * T + iw0 + ll);
        quf[0] = *(const bf16x8*)&qu[qrow * 1024 + qc];
        quf[1] = *(const bf16x8*)&qu[qrow * 1024 + qc + 32];
        qvf[0] = *(const bf16x8*)&qv[qrow * 1024 + qc];
        qvf[1] = *(const bf16x8*)&qv[qrow * 1024 + qc + 32];
    }
    const int r2 = iw0 + ll + 1;
    const size_t qrow2 = (size_t)(b * T + (r2 < T ? r2 : T - 1));
    const u16* kb = kcat + (size_t)b * L * 1024 + h * 64;
    const u16* vb = vcat + (size_t)b * L * 1024 + h * 64;
    const u16* rb = rbuf + h * 64;

    f32x4 o_acc[4] = {};
    f32x4 o_sum = {0.f, 0.f, 0.f, 0.f};
    float m_run[4] = {-1e30f, -1e30f, -1e30f, -1e30f};
    const bf16x8 onesb = {(short)0x3F80, (short)0x3F80, (short)0x3F80, (short)0x3F80,
                          (short)0x3F80, (short)0x3F80, (short)0x3F80, (short)0x3F80};
    const int vjq = tid & 15, vdg = tid >> 4;

    for (int jt = 0; jt < 32; ++jt) {
        const int j0 = jt * 64;
        const bool main_blk = (j0 <= MM + i0 + 63);
        const bool wrap_blk = (j0 + 63 >= MM + i0 + 2);
        __syncthreads();
#pragma unroll
        for (int p = 0; p < 2; ++p) {
            const int k8 = w * 2 + p;
            GLL16(&KtL[k8 * 512], kb + (size_t)(j0 + k8 * 8 + l8) * 1024 + ssrc);
        }
        if (main_blk) {
            const long bm = (long)j0 + T - i0 - 64;
#pragma unroll
            for (int p = 0; p < 4; ++p) {
                const int k8 = w * 4 + p;
                GLL16(&RmL[k8 * 512], rb + (long)(bm + k8 * 8 + l8) * 1024 + ssrc);
            }
        }
        if (wrap_blk) {
            const long bw_ = (long)j0 - MM - i0 - 65;
#pragma unroll
            for (int p = 0; p < 4; ++p) {
                const int k8 = w * 4 + p;
                GLL16(&RwL[k8 * 512], rb + (long)(bw_ + k8 * 8 + l8) * 1024 + ssrc);
            }
        }
        { // V^T stage with j-permutation: rows j = vjq + 16s -> j' = 4*vjq+s
            const u16* srcv = vb + (size_t)(j0 + vjq) * 1024 + vdg * 4;
            const ushort4 r0 = *(const ushort4*)(srcv);
            const ushort4 r1 = *(const ushort4*)(srcv + 16 * 1024);
            const ushort4 r2w = *(const ushort4*)(srcv + 32 * 1024);
            const ushort4 r3 = *(const ushort4*)(srcv + 48 * 1024);
            *(ushort4*)&Vt[vdg * 4 + 0][vjq * 4] = (ushort4){r0.x, r1.x, r2w.x, r3.x};
            *(ushort4*)&Vt[vdg * 4 + 1][vjq * 4] = (ushort4){r0.y, r1.y, r2w.y, r3.y};
            *(ushort4*)&Vt[vdg * 4 + 2][vjq * 4] = (ushort4){r0.z, r1.z, r2w.z, r3.z};
            *(ushort4*)&Vt[vdg * 4 + 3][vjq * 4] = (ushort4){r0.w, r1.w, r2w.w, r3.w};
        }
        __syncthreads();

        f32x4 sv[4];
        __builtin_amdgcn_s_setprio(1);
#pragma unroll
        for (int ns = 0; ns < 4; ++ns) {
            const int rowb = (ns * 16 + ll) * 64;
            f32x4 a = {0.f, 0.f, 0.f, 0.f};
            a = mfma16(quf[0], *(const bf16x8*)&KtL[rowb + sA], a);
            a = mfma16(quf[1], *(const bf16x8*)&KtL[rowb + sB], a);
            sv[ns] = a;
        }
        __builtin_amdgcn_s_setprio(0);

        if (main_blk && j0 <= MM + iw0 + 15) {
            const int trb = 48 - 16 * w;
            f32x4 gb[5];
#pragma unroll
            for (int cs = 0; cs < 5; ++cs) {
                const int rowb = (trb + cs * 16 + ll) * 64;
                f32x4 a = {0.f, 0.f, 0.f, 0.f};
                a = mfma16(qvf[0], *(const bf16x8*)&RmL[rowb + sA], a);
                a = mfma16(qvf[1], *(const bf16x8*)&RmL[rowb + sB], a);
                gb[cs] = a;
            }
#pragma unroll
            for (int r = 0; r < 4; ++r) {
                const int i_loc = lg * 4 + r;
                const int srcl = (l & 48) | ((ll + 15 - i_loc) & 15);
                const float sh0 = __shfl(gb[0][r], srcl, 64);
                const float sh1 = __shfl(gb[1][r], srcl, 64);
                const float sh2 = __shfl(gb[2][r], srcl, 64);
                const float sh3 = __shfl(gb[3][r], srcl, 64);
                const float sh4 = __shfl(gb[4][r], srcl, 64);
                const bool hi = (ll > i_loc);
                const int thr = MM + iw0 + i_loc - j0;
                const float e0 = hi ? sh1 : sh0;
                const float e1 = hi ? sh2 : sh1;
                const float e2 = hi ? sh3 : sh2;
                const float e3 = hi ? sh4 : sh3;
                if (ll <= thr)      sv[0][r] += e0;
                if (16 + ll <= thr) sv[1][r] += e1;
                if (32 + ll <= thr) sv[2][r] += e2;
                if (48 + ll <= thr) sv[3][r] += e3;
            }
        }
        if (wrap_blk && j0 + 63 >= MM + iw0 + 2) {
            const bf16x8 qv2f0 = *(const bf16x8*)&qv[qrow2 * 1024 + qc];
            const bf16x8 qv2f1 = *(const bf16x8*)&qv[qrow2 * 1024 + qc + 32];
            const int trb = 48 - 16 * w;
            f32x4 gb[5];
#pragma unroll
            for (int cs = 0; cs < 5; ++cs) {
                const int rowb = (trb + cs * 16 + ll) * 64;
                f32x4 a = {0.f, 0.f, 0.f, 0.f};
                a = mfma16(qv2f0, *(const bf16x8*)&RwL[rowb + sA], a);
                a = mfma16(qv2f1, *(const bf16x8*)&RwL[rowb + sB], a);
                gb[cs] = a;
            }
#pragma unroll
            for (int r = 0; r < 4; ++r) {
                const int i_loc = lg * 4 + r;
                const int srcl = (l & 48) | ((ll + 15 - i_loc) & 15);
                const float sh0 = __shfl(gb[0][r], srcl, 64);
                const float sh1 = __shfl(gb[1][r], srcl, 64);
                const float sh2 = __shfl(gb[2][r], srcl, 64);
                const float sh3 = __shfl(gb[3][r], srcl, 64);
                const float sh4 = __shfl(gb[4][r], srcl, 64);
                const bool hi = (ll > i_loc);
                const int thr2 = MM + iw0 + i_loc - j0 + 2;
                const float e0 = hi ? sh1 : sh0;
                const float e1 = hi ? sh2 : sh1;
                const float e2 = hi ? sh3 : sh2;
                const float e3 = hi ? sh4 : sh3;
                if (ll >= thr2)      sv[0][r] += e0;
                if (16 + ll >= thr2) sv[1][r] += e1;
                if (32 + ll >= thr2) sv[2][r] += e2;
                if (48 + ll >= thr2) sv[3][r] += e3;
            }
        }

#pragma unroll
        for (int r = 0; r < 4; ++r) {
            const int i_loc = lg * 4 + r;
            const float s0 = sv[0][r] * 0.125f, s1 = sv[1][r] * 0.125f;
            const float s2 = sv[2][r] * 0.125f, s3 = sv[3][r] * 0.125f;
            float pm = fmaxf(fmaxf(s0, s1), fmaxf(s2, s3));
            pm = fmaxf(pm, __shfl_xor(pm, 1, 64));
            pm = fmaxf(pm, __shfl_xor(pm, 2, 64));
            pm = fmaxf(pm, __shfl_xor(pm, 4, 64));
            pm = fmaxf(pm, __shfl_xor(pm, 8, 64));
            const float mnew = fmaxf(m_run[r], pm);
            const float alpha = __expf(m_run[r] - mnew);
            const float p0 = __expf(s0 - mnew), p1 = __expf(s1 - mnew);
            const float p2 = __expf(s2 - mnew), p3 = __expf(s3 - mnew);
            const ushort4 pw = {f2bf(p0), f2bf(p1), f2bf(p2), f2bf(p3)};
            *(ushort4*)&Pl[w][i_loc][ll * 4] = pw;
            m_run[r] = mnew;
            o_sum[r] *= alpha;
#pragma unroll
            for (int ns = 0; ns < 4; ++ns) o_acc[ns][r] *= alpha;
        }

        __builtin_amdgcn_s_setprio(1);
        const bf16x8 ap0 = *(const bf16x8*)&Pl[w][ll][lg * 8];
        const bf16x8 ap1 = *(const bf16x8*)&Pl[w][ll][32 + lg * 8];
#pragma unroll
        for (int ns = 0; ns < 4; ++ns) {
            const bf16x8 bv0 = *(const bf16x8*)&Vt[ns * 16 + ll][lg * 8];
            const bf16x8 bv1 = *(const bf16x8*)&Vt[ns * 16 + ll][32 + lg * 8];
            o_acc[ns] = mfma16(ap0, bv0, o_acc[ns]);
            o_acc[ns] = mfma16(ap1, bv1, o_acc[ns]);
        }
        o_sum = mfma16(ap0, onesb, o_sum);
        o_sum = mfma16(ap1, onesb, o_sum);
        __builtin_amdgcn_s_setprio(0);
    }

#pragma unroll
    for (int ns = 0; ns < 4; ++ns)
#pragma unroll
        for (int r = 0; r < 4; ++r) {
            const int row = iw0 + lg * 4 + r;
            outp[(size_t)(b * T + row) * 1024 + h * 64 + ns * 16 + ll] =
                f2bf(o_acc[ns][r] / o_sum[r]);
        }
}

// ------------------------------- launch ---------------------------------
extern "C" void kernel_launch(void* const* d_in, const int* in_sizes, int n_in,
                              void* d_out, int out_size, void* d_ws, size_t ws_size,
                              hipStream_t stream) {
    const float* x    = (const float*)d_in[0];
    const float* mem  = (const float*)d_in[1];
    const float* Wq   = (const float*)d_in[2];
    const float* Wk   = (const float*)d_in[3];
    const float* Wv   = (const float*)d_in[4];
    const float* Wr   = (const float*)d_in[5];
    const float* Wo   = (const float*)d_in[6];
    const float* bu   = (const float*)d_in[7];
    const float* bv   = (const float*)d_in[8];
    const float* ln1g = (const float*)d_in[9];
    const float* ln1b = (const float*)d_in[10];
    const float* ln2g = (const float*)d_in[11];
    const float* ln2b = (const float*)d_in[12];
    const float* W1   = (const float*)d_in[13];
    const float* b1   = (const float*)d_in[14];
    const float* W2   = (const float*)d_in[15];
    const float* b2   = (const float*)d_in[16];

    float* y_out   = (float*)d_out;
    float* mem_out = (float*)d_out + 4194304;

    // ===== d_out (32 MB fp32) as scratch, time-multiplexed =====
    char* dob = (char*)d_out;
    u16* attno     = (u16*)(dob + 0);
    u16* pe        = (u16*)(dob + (size_t)8  * 1048576);
    u16* rbuf_base = (u16*)(dob + (size_t)12 * 1048576);
    u16* rbuf      = rbuf_base + 80 * 1024;           // padded +/-80 rows
    char* dw = dob + (size_t)16 * 1048576 + 524288;   // 16.5 MB
    u16* WqT = (u16*)(dw);
    u16* WkT = (u16*)(dw + (size_t)2 * 1048576);
    u16* WvT = (u16*)(dw + (size_t)4 * 1048576);
    u16* WrT = (u16*)(dw + (size_t)6 * 1048576);
    u16* WoT = (u16*)(dw + (size_t)8 * 1048576);

    // ===== ws layout, extent 64 MB =====
    char* ws = (char*)d_ws;
    const size_t MB = 1u << 20;
    u16*  xn    = (u16*)(ws + 0 * MB);
    u16*  x2n   = (u16*)(ws + 0 * MB);
    u16*  W2T   = (u16*)(ws + 0 * MB);
    u16*  qu    = (u16*)(ws + 8 * MB);
    float* x2f  = (float*)(ws + 8 * MB);
    u16*  qv    = (u16*)(ws + 16 * MB);
    u16*  kcat  = (u16*)(ws + 24 * MB);
    u16*  ffh   = (u16*)(ws + 24 * MB);
    u16*  vcat  = (u16*)(ws + 40 * MB);
    u16*  memb  = (u16*)(ws + 56 * MB);
    u16*  W1T   = (u16*)(ws + 56 * MB);

    transpose5_kernel<<<dim3(32, 32, 5), 256, 0, stream>>>(Wq, Wk, Wv, Wr, Wo,
                                                           WqT, WkT, WvT, WrT, WoT);
    pe_kernel<<<8192, 256, 0, stream>>>(pe);
    convert_kernel<<<2048, 256, 0, stream>>>(mem, memb);
    ln_kernel<<<1024, 256, 0, stream>>>(x, ln1g, ln1b, xn);
    gemm64_kernel<0><<<dim3(32, 8), 256, 0, stream>>>(pe, WrT, rbuf, nullptr, nullptr, nullptr, nullptr, 2048, 1024, 1024);
    gemm64_kernel<1><<<dim3(64, 8), 256, 0, stream>>>(xn, WqT, qu, qv, bu, bv, nullptr, 4096, 1024, 1024);
    gemm_kv_kernel<<<dim3(64, 8), 256, 0, stream>>>(memb, xn, WkT, WvT, kcat, vcat);
    attn_kernel<<<1024, 256, 0, stream>>>(qu, qv, kcat, vcat, rbuf, attno);
    gemm64_kernel<2><<<dim3(64, 8), 256, 0, stream>>>(attno, WoT, x2f, nullptr, nullptr, nullptr, x, 4096, 1024, 1024);
    transpose_kernel<<<dim3(128, 32), 256, 0, stream>>>(W1, W1T, 1024, 4096);
    hipMemcpyAsync(mem_out, x, (size_t)4194304 * 4, hipMemcpyDeviceToDevice, stream);
    ln_kernel<<<1024, 256, 0, stream>>>(x2f, ln2g, ln2b, x2n);
    gemm_kernel<3, false><<<dim3(32, 32), 256, 0, stream>>>(x2n, nullptr, W1T, ffh, nullptr, b1, nullptr, nullptr, 4096, 4096, 1024);
    transpose_kernel<<<dim3(32, 128), 256, 0, stream>>>(W2, W2T, 4096, 1024);
    gemm64_kernel<4><<<dim3(64, 8), 256, 0, stream>>>(ffh, W2T, y_out, nullptr, b2, nullptr, x2f, 4096, 1024, 4096);
    (void)in_sizes; (void)n_in; (void)out_size; (void)ws_size;
}

// Round 20
// 491.679 us; speedup vs baseline: 1.1234x; 1.0041x over previous
//
#include <hip/hip_runtime.h>
#include <hip/hip_bf16.h>

typedef short bf16x8 __attribute__((ext_vector_type(8)));
typedef float f32x4 __attribute__((ext_vector_type(4)));
typedef unsigned short u16;

__device__ __forceinline__ float bf2f(u16 u) {
    union { unsigned int i; float f; } x; x.i = ((unsigned int)u) << 16; return x.f;
}
__device__ __forceinline__ u16 f2bf(float f) {
    union { float f; unsigned int i; } x; x.f = f;
    unsigned int r = x.i + 0x7fff + ((x.i >> 16) & 1);
    return (u16)(r >> 16);
}
__device__ __forceinline__ f32x4 mfma16(bf16x8 a, bf16x8 b, f32x4 c) {
    return __builtin_amdgcn_mfma_f32_16x16x32_bf16(a, b, c, 0, 0, 0);
}
#define GLL16(lds_base, gsrc) \
    __builtin_amdgcn_global_load_lds((const __attribute__((address_space(1))) void*)(gsrc), \
                                     (__attribute__((address_space(3))) void*)(lds_base), 16, 0, 0)

// ------------- fused transpose of five 1024x1024 weights ----------------
__global__ __launch_bounds__(256)
void transpose5_kernel(const float* __restrict__ s0, const float* __restrict__ s1,
                       const float* __restrict__ s2, const float* __restrict__ s3,
                       const float* __restrict__ s4,
                       u16* __restrict__ d0, u16* __restrict__ d1,
                       u16* __restrict__ d2, u16* __restrict__ d3,
                       u16* __restrict__ d4) {
    const float* in; u16* out;
    switch (blockIdx.z) {
        case 0: in = s0; out = d0; break;
        case 1: in = s1; out = d1; break;
        case 2: in = s2; out = d2; break;
        case 3: in = s3; out = d3; break;
        default: in = s4; out = d4; break;
    }
    __shared__ float t[32][33];
    const int c0 = blockIdx.x * 32, r0 = blockIdx.y * 32;
    const int tx = threadIdx.x & 31, ty = threadIdx.x >> 5;
#pragma unroll
    for (int i = 0; i < 32; i += 8) t[ty + i][tx] = in[(size_t)(r0 + ty + i) * 1024 + c0 + tx];
    __syncthreads();
#pragma unroll
    for (int i = 0; i < 32; i += 8) out[(size_t)(c0 + ty + i) * 1024 + r0 + tx] = f2bf(t[tx][ty + i]);
}

// ------------- transpose fp32 [R][C] -> bf16 [C][R] ---------------------
__global__ __launch_bounds__(256)
void transpose_kernel(const float* __restrict__ in, u16* __restrict__ out, int R, int C) {
    __shared__ float t[32][33];
    const int c0 = blockIdx.x * 32, r0 = blockIdx.y * 32;
    const int tx = threadIdx.x & 31, ty = threadIdx.x >> 5;
#pragma unroll
    for (int i = 0; i < 32; i += 8) t[ty + i][tx] = in[(size_t)(r0 + ty + i) * C + c0 + tx];
    __syncthreads();
#pragma unroll
    for (int i = 0; i < 32; i += 8) out[(size_t)(c0 + ty + i) * R + r0 + tx] = f2bf(t[tx][ty + i]);
}

// ------------- fp32 -> bf16 convert (8 elems/thread) --------------------
__global__ __launch_bounds__(256)
void convert_kernel(const float* __restrict__ in, u16* __restrict__ out) {
    const size_t i = ((size_t)blockIdx.x * 256 + threadIdx.x) * 8;
    const float4 a = *(const float4*)(in + i);
    const float4 b = *(const float4*)(in + i + 4);
    bf16x8 o;
    o[0] = (short)f2bf(a.x); o[1] = (short)f2bf(a.y);
    o[2] = (short)f2bf(a.z); o[3] = (short)f2bf(a.w);
    o[4] = (short)f2bf(b.x); o[5] = (short)f2bf(b.y);
    o[6] = (short)f2bf(b.z); o[7] = (short)f2bf(b.w);
    *(bf16x8*)(out + i) = o;
}

// ------------- positional embedding pe[2048][1024] (bf16) ---------------
__global__ __launch_bounds__(256)
void pe_kernel(u16* __restrict__ pe) {
    const int idx = blockIdx.x * 256 + threadIdx.x;
    const int p = idx >> 10, d = idx & 1023;
    const float pos = (float)(2047 - p);
    const int k = d & 511;
    const float invf = powf(10000.f, ((float)(2 * k)) * (-1.f / 1024.f));
    const float a = pos * invf;
    pe[idx] = f2bf((d < 512) ? sinf(a) : cosf(a));
}

// ------------- LayerNorm (fp32 in, bf16 out), one wave per row ----------
__global__ __launch_bounds__(256)
void ln_kernel(const float* __restrict__ inp, const float* __restrict__ gg,
               const float* __restrict__ bb, u16* __restrict__ outp) {
    const int row = blockIdx.x * 4 + (threadIdx.x >> 6);
    const int l = threadIdx.x & 63;
    const size_t base = (size_t)row * 1024 + l * 16;
    float v[16];
    const float4* p4 = (const float4*)(inp + base);
#pragma unroll
    for (int j = 0; j < 4; ++j) {
        float4 f = p4[j];
        v[j*4+0] = f.x; v[j*4+1] = f.y; v[j*4+2] = f.z; v[j*4+3] = f.w;
    }
    float s = 0.f, s2 = 0.f;
#pragma unroll
    for (int j = 0; j < 16; ++j) { s += v[j]; s2 += v[j] * v[j]; }
#pragma unroll
    for (int off = 1; off < 64; off <<= 1) {
        s += __shfl_xor(s, off, 64);
        s2 += __shfl_xor(s2, off, 64);
    }
    const float mu = s * 0.0009765625f;
    const float var = s2 * 0.0009765625f - mu * mu;
    const float rs = rsqrtf(var + 1e-5f);
#pragma unroll
    for (int j = 0; j < 16; ++j)
        outp[base + j] = f2bf((v[j] - mu) * rs * gg[l * 16 + j] + bb[l * 16 + j]);
}

// ---------------- GEMM 128x128, BK=64, XOR-swizzled (FF1/GELU) ----------
template<int EPI>
__global__ __launch_bounds__(256)
void gemm128_kernel(const u16* __restrict__ A, const u16* __restrict__ Wt,
                    void* __restrict__ outp, const float* __restrict__ cb1,
                    int Mdim, int Ndim, int Kdim) {
    __shared__ __attribute__((aligned(16))) u16 As[128 * 64];   // 16KB swz
    __shared__ __attribute__((aligned(16))) u16 Bs[128 * 64];   // 16KB swz
    const int tid = threadIdx.x;
    const int w = tid >> 6, l = tid & 63;
    const int lg = l >> 4, ll = l & 15;
    const int wr = w >> 1, wc = w & 1;
    const int l8 = l >> 3;
    const int ssrc = ((l & 7) * 8) ^ (l8 << 3);
    const int m0 = blockIdx.x * 128, n0 = blockIdx.y * 128;
    f32x4 acc[4][4] = {};

    for (int k0 = 0; k0 < Kdim; k0 += 64) {
        __syncthreads();
#pragma unroll
        for (int p = 0; p < 4; ++p) {
            const int k8 = w * 4 + p;
            GLL16(&As[k8 * 512], A + (size_t)(m0 + k8 * 8 + l8) * Kdim + k0 + ssrc);
            GLL16(&Bs[k8 * 512], Wt + (size_t)(n0 + k8 * 8 + l8) * Kdim + k0 + ssrc);
        }
        __syncthreads();
#pragma unroll
        for (int kk = 0; kk < 2; ++kk) {
            const int cA = ((kk * 4 + lg) * 8) ^ ((ll & 7) << 3);
            bf16x8 af[4], bfr[4];
#pragma unroll
            for (int mi = 0; mi < 4; ++mi)
                af[mi] = *(const bf16x8*)&As[(wr * 64 + mi * 16 + ll) * 64 + cA];
#pragma unroll
            for (int ni = 0; ni < 4; ++ni)
                bfr[ni] = *(const bf16x8*)&Bs[(wc * 64 + ni * 16 + ll) * 64 + cA];
#pragma unroll
            for (int mi = 0; mi < 4; ++mi)
#pragma unroll
                for (int ni = 0; ni < 4; ++ni)
                    acc[mi][ni] = mfma16(af[mi], bfr[ni], acc[mi][ni]);
        }
    }

#pragma unroll
    for (int mi = 0; mi < 4; ++mi)
#pragma unroll
        for (int ni = 0; ni < 4; ++ni)
#pragma unroll
            for (int rg = 0; rg < 4; ++rg) {
                const int row = m0 + wr * 64 + mi * 16 + lg * 4 + rg;
                const int col = n0 + wc * 64 + ni * 16 + ll;
                const size_t idx = (size_t)row * Ndim + col;
                const float v = acc[mi][ni][rg];
                if (EPI == 3) { // + bias, exact GELU, bf16 out
                    const float t = v + cb1[col];
                    ((u16*)outp)[idx] = f2bf(0.5f * t * (1.f + erff(t * 0.70710678118654752f)));
                } else {
                    ((u16*)outp)[idx] = f2bf(v);
                }
            }
}

// ---------------- GEMM 64x128, BK=64, XOR-swizzled LDS ------------------
template<int EPI>
__global__ __launch_bounds__(256)
void gemm64_kernel(const u16* __restrict__ A, const u16* __restrict__ Wt,
                   void* __restrict__ outp, u16* __restrict__ out2,
                   const float* __restrict__ cb1, const float* __restrict__ cb2,
                   const float* __restrict__ residp,
                   int Mdim, int Ndim, int Kdim) {
    __shared__ __attribute__((aligned(16))) u16 As[64 * 64];    // 8KB swz
    __shared__ __attribute__((aligned(16))) u16 Bs[128 * 64];   // 16KB swz
    const int tid = threadIdx.x;
    const int w = tid >> 6, l = tid & 63;
    const int lg = l >> 4, ll = l & 15;
    const int l8 = l >> 3;
    const int ssrc = ((l & 7) * 8) ^ (l8 << 3);
    const int m0 = blockIdx.x * 64, n0 = blockIdx.y * 128;
    f32x4 acc[4][2] = {};

    for (int k0 = 0; k0 < Kdim; k0 += 64) {
        __syncthreads();
#pragma unroll
        for (int p = 0; p < 2; ++p) {   // A rows 0..63
            const int k8 = w * 2 + p;
            GLL16(&As[k8 * 512], A + (size_t)(m0 + k8 * 8 + l8) * Kdim + k0 + ssrc);
        }
#pragma unroll
        for (int p = 0; p < 4; ++p) {   // B rows 0..127
            const int k8 = w * 4 + p;
            GLL16(&Bs[k8 * 512], Wt + (size_t)(n0 + k8 * 8 + l8) * Kdim + k0 + ssrc);
        }
        __syncthreads();
#pragma unroll
        for (int kk = 0; kk < 2; ++kk) {
            const int cA = ((kk * 4 + lg) * 8) ^ ((ll & 7) << 3);
            bf16x8 af[4], bfr[2];
#pragma unroll
            for (int mi = 0; mi < 4; ++mi)
                af[mi] = *(const bf16x8*)&As[(mi * 16 + ll) * 64 + cA];
#pragma unroll
            for (int ni = 0; ni < 2; ++ni)
                bfr[ni] = *(const bf16x8*)&Bs[(w * 32 + ni * 16 + ll) * 64 + cA];
#pragma unroll
            for (int mi = 0; mi < 4; ++mi)
#pragma unroll
                for (int ni = 0; ni < 2; ++ni)
                    acc[mi][ni] = mfma16(af[mi], bfr[ni], acc[mi][ni]);
        }
    }

#pragma unroll
    for (int mi = 0; mi < 4; ++mi)
#pragma unroll
        for (int ni = 0; ni < 2; ++ni)
#pragma unroll
            for (int rg = 0; rg < 4; ++rg) {
                const int row = m0 + mi * 16 + lg * 4 + rg;
                const int col = n0 + w * 32 + ni * 16 + ll;
                const size_t idx = (size_t)row * Ndim + col;
                const float v = acc[mi][ni][rg];
                if (EPI == 0) {
                    ((u16*)outp)[idx] = f2bf(v);
                } else if (EPI == 1) {
                    ((u16*)outp)[idx] = f2bf(v + cb1[col]);
                    out2[idx] = f2bf(v + cb2[col]);
                } else if (EPI == 2) {
                    ((float*)outp)[idx] = v + residp[idx];
                } else {
                    ((float*)outp)[idx] = v + cb1[col] + residp[idx]; // fp32 y
                }
            }
}

// ---------------- fused K+V GEMM: BK=64, swizzled, A staged once --------
__global__ __launch_bounds__(256)
void gemm_kv_kernel(const u16* __restrict__ A, const u16* __restrict__ A2,
                    const u16* __restrict__ WtK, const u16* __restrict__ WtV,
                    u16* __restrict__ outK, u16* __restrict__ outV) {
    __shared__ __attribute__((aligned(16))) u16 As[128 * 64];   // 16KB swz
    __shared__ __attribute__((aligned(16))) u16 Bk[128 * 64];   // 16KB swz
    __shared__ __attribute__((aligned(16))) u16 Bv[128 * 64];   // 16KB swz
    const int tid = threadIdx.x;
    const int w = tid >> 6, l = tid & 63;
    const int lg = l >> 4, ll = l & 15;
    const int wr = w >> 1, wc = w & 1;
    const int l8 = l >> 3;
    const int ssrc = ((l & 7) * 8) ^ (l8 << 3);
    const int m0 = blockIdx.x * 128, n0 = blockIdx.y * 128;
    f32x4 acck[4][4] = {};
    f32x4 accv[4][4] = {};

    for (int k0 = 0; k0 < 1024; k0 += 64) {
        __syncthreads();
#pragma unroll
        for (int p = 0; p < 4; ++p) {
            const int k8 = w * 4 + p;
            const int rr = m0 + k8 * 8 + l8;
            const int bb_ = rr >> 11, pos = rr & 2047;
            const u16* srcA = (pos < 1024 ? A + ((size_t)(bb_ * 1024 + pos)) * 1024
                                          : A2 + ((size_t)(bb_ * 1024 + pos - 1024)) * 1024)
                              + k0 + ssrc;
            GLL16(&As[k8 * 512], srcA);
            GLL16(&Bk[k8 * 512], WtK + (size_t)(n0 + k8 * 8 + l8) * 1024 + k0 + ssrc);
            GLL16(&Bv[k8 * 512], WtV + (size_t)(n0 + k8 * 8 + l8) * 1024 + k0 + ssrc);
        }
        __syncthreads();
#pragma unroll
        for (int kk = 0; kk < 2; ++kk) {
            const int cA = ((kk * 4 + lg) * 8) ^ ((ll & 7) << 3);
            bf16x8 af[4], bkf[4], bvf[4];
#pragma unroll
            for (int mi = 0; mi < 4; ++mi)
                af[mi] = *(const bf16x8*)&As[(wr * 64 + mi * 16 + ll) * 64 + cA];
#pragma unroll
            for (int ni = 0; ni < 4; ++ni) {
                const int off = (wc * 64 + ni * 16 + ll) * 64 + cA;
                bkf[ni] = *(const bf16x8*)&Bk[off];
                bvf[ni] = *(const bf16x8*)&Bv[off];
            }
#pragma unroll
            for (int mi = 0; mi < 4; ++mi)
#pragma unroll
                for (int ni = 0; ni < 4; ++ni) {
                    acck[mi][ni] = mfma16(af[mi], bkf[ni], acck[mi][ni]);
                    accv[mi][ni] = mfma16(af[mi], bvf[ni], accv[mi][ni]);
                }
        }
    }

#pragma unroll
    for (int mi = 0; mi < 4; ++mi)
#pragma unroll
        for (int ni = 0; ni < 4; ++ni)
#pragma unroll
            for (int rg = 0; rg < 4; ++rg) {
                const int row = m0 + wr * 64 + mi * 16 + lg * 4 + rg;
                const int col = n0 + wc * 64 + ni * 16 + ll;
                const size_t idx = (size_t)row * 1024 + col;
                outK[idx] = f2bf(acck[mi][ni][rg]);
                outV[idx] = f2bf(accv[mi][ni][rg]);
            }
}

// ---------------- fused rel-attention (R16 best: j-perm P/V, ones-sum) --
__global__ __launch_bounds__(256, 2)
void attn_kernel(const u16* __restrict__ qu, const u16* __restrict__ qv,
                 const u16* __restrict__ kcat, const u16* __restrict__ vcat,
                 const u16* __restrict__ rbuf, u16* __restrict__ outp) {
    constexpr int T = 1024, L = 2048, MM = 1024;
    __shared__ __attribute__((aligned(16))) u16 KtL[64 * 64];   // 8KB swz
    __shared__ __attribute__((aligned(16))) u16 RmL[128 * 64];  // 16KB swz
    __shared__ __attribute__((aligned(16))) u16 RwL[128 * 64];  // 16KB swz
    __shared__ __attribute__((aligned(16))) u16 Vt[64][72];     // 9KB (j')
    __shared__ __attribute__((aligned(16))) u16 Pl[4][16][72];  // 9KB (j')
    const int bid = blockIdx.x;
    const int g = (bid & 7) + 8 * (bid >> 7);   // head-group (XCD swizzle)
    const int it = (bid >> 3) & 15;
    const int h = g & 15, b = g >> 4;
    const int i0 = it * 64;
    const int tid = threadIdx.x;
    const int w = tid >> 6, l = tid & 63;
    const int lg = l >> 4, ll = l & 15;
    const int iw0 = i0 + w * 16;
    const int l8 = l >> 3;
    const int ssrc = ((l & 7) * 8) ^ (l8 << 3);
    const int sA = (lg * 8) ^ ((ll & 7) << 3);
    const int sB = (lg * 8 + 32) ^ ((ll & 7) << 3);

    bf16x8 quf[2], qvf[2];
    const int qc = h * 64 + lg * 8;
    {
        const size_t qrow = (size_t)(b * T + iw0 + ll);
        quf[0] = *(const bf16x8*)&qu[qrow * 1024 + qc];
        quf[1] = *(const bf16x8*)&qu[qrow * 1024 + qc + 32];
        qvf[0] = *(const bf16x8*)&qv[qrow * 1024 + qc];
        qvf[1] = *(const bf16x8*)&qv[qrow * 1024 + qc + 32];
    }
    const int r2 = iw0 + ll + 1;
    const size_t qrow2 = (size_t)(b * T + (r2 < T ? r2 : T - 1));
    const u16* kb = kcat + (size_t)b * L * 1024 + h * 64;
    const u16* vb = vcat + (size_t)b * L * 1024 + h * 64;
    const u16* rb = rbuf + h * 64;

    f32x4 o_acc[4] = {};
    f32x4 o_sum = {0.f, 0.f, 0.f, 0.f};
    float m_run[4] = {-1e30f, -1e30f, -1e30f, -1e30f};
    const bf16x8 onesb = {(short)0x3F80, (short)0x3F80, (short)0x3F80, (short)0x3F80,
                          (short)0x3F80, (short)0x3F80, (short)0x3F80, (short)0x3F80};
    const int vjq = tid & 15, vdg = tid >> 4;

    for (int jt = 0; jt < 32; ++jt) {
        const int j0 = jt * 64;
        const bool main_blk = (j0 <= MM + i0 + 63);
        const bool wrap_blk = (j0 + 63 >= MM + i0 + 2);
        __syncthreads();
#pragma unroll
        for (int p = 0; p < 2; ++p) {
            const int k8 = w * 2 + p;
            GLL16(&KtL[k8 * 512], kb + (size_t)(j0 + k8 * 8 + l8) * 1024 + ssrc);
        }
        if (main_blk) {
            const long bm = (long)j0 + T - i0 - 64;
#pragma unroll
            for (int p = 0; p < 4; ++p) {
                const int k8 = w * 4 + p;
                GLL16(&RmL[k8 * 512], rb + (long)(bm + k8 * 8 + l8) * 1024 + ssrc);
            }
        }
        if (wrap_blk) {
            const long bw_ = (long)j0 - MM - i0 - 65;
#pragma unroll
            for (int p = 0; p < 4; ++p) {
                const int k8 = w * 4 + p;
                GLL16(&RwL[k8 * 512], rb + (long)(bw_ + k8 * 8 + l8) * 1024 + ssrc);
            }
        }
        { // V^T stage with j-permutation: rows j = vjq + 16s -> j' = 4*vjq+s
            const u16* srcv = vb + (size_t)(j0 + vjq) * 1024 + vdg * 4;
            const ushort4 r0 = *(const ushort4*)(srcv);
            const ushort4 r1 = *(const ushort4*)(srcv + 16 * 1024);
            const ushort4 r2w = *(const ushort4*)(srcv + 32 * 1024);
            const ushort4 r3 = *(const ushort4*)(srcv + 48 * 1024);
            *(ushort4*)&Vt[vdg * 4 + 0][vjq * 4] = (ushort4){r0.x, r1.x, r2w.x, r3.x};
            *(ushort4*)&Vt[vdg * 4 + 1][vjq * 4] = (ushort4){r0.y, r1.y, r2w.y, r3.y};
            *(ushort4*)&Vt[vdg * 4 + 2][vjq * 4] = (ushort4){r0.z, r1.z, r2w.z, r3.z};
            *(ushort4*)&Vt[vdg * 4 + 3][vjq * 4] = (ushort4){r0.w, r1.w, r2w.w, r3.w};
        }
        __syncthreads();

        f32x4 sv[4];
        __builtin_amdgcn_s_setprio(1);
#pragma unroll
        for (int ns = 0; ns < 4; ++ns) {
            const int rowb = (ns * 16 + ll) * 64;
            f32x4 a = {0.f, 0.f, 0.f, 0.f};
            a = mfma16(quf[0], *(const bf16x8*)&KtL[rowb + sA], a);
            a = mfma16(quf[1], *(const bf16x8*)&KtL[rowb + sB], a);
            sv[ns] = a;
        }
        __builtin_amdgcn_s_setprio(0);

        if (main_blk && j0 <= MM + iw0 + 15) {
            const int trb = 48 - 16 * w;
            f32x4 gb[5];
#pragma unroll
            for (int cs = 0; cs < 5; ++cs) {
                const int rowb = (trb + cs * 16 + ll) * 64;
                f32x4 a = {0.f, 0.f, 0.f, 0.f};
                a = mfma16(qvf[0], *(const bf16x8*)&RmL[rowb + sA], a);
                a = mfma16(qvf[1], *(const bf16x8*)&RmL[rowb + sB], a);
                gb[cs] = a;
            }
#pragma unroll
            for (int r = 0; r < 4; ++r) {
                const int i_loc = lg * 4 + r;
                const int srcl = (l & 48) | ((ll + 15 - i_loc) & 15);
                const float sh0 = __shfl(gb[0][r], srcl, 64);
                const float sh1 = __shfl(gb[1][r], srcl, 64);
                const float sh2 = __shfl(gb[2][r], srcl, 64);
                const float sh3 = __shfl(gb[3][r], srcl, 64);
                const float sh4 = __shfl(gb[4][r], srcl, 64);
                const bool hi = (ll > i_loc);
                const int thr = MM + iw0 + i_loc - j0;
                const float e0 = hi ? sh1 : sh0;
                const float e1 = hi ? sh2 : sh1;
                const float e2 = hi ? sh3 : sh2;
                const float e3 = hi ? sh4 : sh3;
                if (ll <= thr)      sv[0][r] += e0;
                if (16 + ll <= thr) sv[1][r] += e1;
                if (32 + ll <= thr) sv[2][r] += e2;
                if (48 + ll <= thr) sv[3][r] += e3;
            }
        }
        if (wrap_blk && j0 + 63 >= MM + iw0 + 2) {
            const bf16x8 qv2f0 = *(const bf16x8*)&qv[qrow2 * 1024 + qc];
            const bf16x8 qv2f1 = *(const bf16x8*)&qv[qrow2 * 1024 + qc + 32];
            const int trb = 48 - 16 * w;
            f32x4 gb[5];
#pragma unroll
            for (int cs = 0; cs < 5; ++cs) {
                const int rowb = (trb + cs * 16 + ll) * 64;
                f32x4 a = {0.f, 0.f, 0.f, 0.f};
                a = mfma16(qv2f0, *(const bf16x8*)&RwL[rowb + sA], a);
                a = mfma16(qv2f1, *(const bf16x8*)&RwL[rowb + sB], a);
                gb[cs] = a;
            }
#pragma unroll
            for (int r = 0; r < 4; ++r) {
                const int i_loc = lg * 4 + r;
                const int srcl = (l & 48) | ((ll + 15 - i_loc) & 15);
                const float sh0 = __shfl(gb[0][r], srcl, 64);
                const float sh1 = __shfl(gb[1][r], srcl, 64);
                const float sh2 = __shfl(gb[2][r], srcl, 64);
                const float sh3 = __shfl(gb[3][r], srcl, 64);
                const float sh4 = __shfl(gb[4][r], srcl, 64);
                const bool hi = (ll > i_loc);
                const int thr2 = MM + iw0 + i_loc - j0 + 2;
                const float e0 = hi ? sh1 : sh0;
                const float e1 = hi ? sh2 : sh1;
                const float e2 = hi ? sh3 : sh2;
                const float e3 = hi ? sh4 : sh3;
                if (ll >= thr2)      sv[0][r] += e0;
                if (16 + ll >= thr2) sv[1][r] += e1;
                if (32 + ll >= thr2) sv[2][r] += e2;
                if (48 + ll >= thr2) sv[3][r] += e3;
            }
        }

#pragma unroll
        for (int r = 0; r < 4; ++r) {
            const int i_loc = lg * 4 + r;
            const float s0 = sv[0][r] * 0.125f, s1 = sv[1][r] * 0.125f;
            const float s2 = sv[2][r] * 0.125f, s3 = sv[3][r] * 0.125f;
            float pm = fmaxf(fmaxf(s0, s1), fmaxf(s2, s3));
            pm = fmaxf(pm, __shfl_xor(pm, 1, 64));
            pm = fmaxf(pm, __shfl_xor(pm, 2, 64));
            pm = fmaxf(pm, __shfl_xor(pm, 4, 64));
            pm = fmaxf(pm, __shfl_xor(pm, 8, 64));
            const float mnew = fmaxf(m_run[r], pm);
            const float alpha = __expf(m_run[r] - mnew);
            const float p0 = __expf(s0 - mnew), p1 = __expf(s1 - mnew);
            const float p2 = __expf(s2 - mnew), p3 = __expf(s3 - mnew);
            const ushort4 pw = {f2bf(p0), f2bf(p1), f2bf(p2), f2bf(p3)};
            *(ushort4*)&Pl[w][i_loc][ll * 4] = pw;
            m_run[r] = mnew;
            o_sum[r] *= alpha;
#pragma unroll
            for (int ns = 0; ns < 4; ++ns) o_acc[ns][r] *= alpha;
        }

        __builtin_amdgcn_s_setprio(1);
        const bf16x8 ap0 = *(const bf16x8*)&Pl[w][ll][lg * 8];
        const bf16x8 ap1 = *(const bf16x8*)&Pl[w][ll][32 + lg * 8];
#pragma unroll
        for (int ns = 0; ns < 4; ++ns) {
            const bf16x8 bv0 = *(const bf16x8*)&Vt[ns * 16 + ll][lg * 8];
            const bf16x8 bv1 = *(const bf16x8*)&Vt[ns * 16 + ll][32 + lg * 8];
            o_acc[ns] = mfma16(ap0, bv0, o_acc[ns]);
            o_acc[ns] = mfma16(ap1, bv1, o_acc[ns]);
        }
        o_sum = mfma16(ap0, onesb, o_sum);
        o_sum = mfma16(ap1, onesb, o_sum);
        __builtin_amdgcn_s_setprio(0);
    }

#pragma unroll
    for (int ns = 0; ns < 4; ++ns)
#pragma unroll
        for (int r = 0; r < 4; ++r) {
            const int row = iw0 + lg * 4 + r;
            outp[(size_t)(b * T + row) * 1024 + h * 64 + ns * 16 + ll] =
                f2bf(o_acc[ns][r] / o_sum[r]);
        }
}

// ------------------------------- launch ---------------------------------
extern "C" void kernel_launch(void* const* d_in, const int* in_sizes, int n_in,
                              void* d_out, int out_size, void* d_ws, size_t ws_size,
                              hipStream_t stream) {
    const float* x    = (const float*)d_in[0];
    const float* mem  = (const float*)d_in[1];
    const float* Wq   = (const float*)d_in[2];
    const float* Wk   = (const float*)d_in[3];
    const float* Wv   = (const float*)d_in[4];
    const float* Wr   = (const float*)d_in[5];
    const float* Wo   = (const float*)d_in[6];
    const float* bu   = (const float*)d_in[7];
    const float* bv   = (const float*)d_in[8];
    const float* ln1g = (const float*)d_in[9];
    const float* ln1b = (const float*)d_in[10];
    const float* ln2g = (const float*)d_in[11];
    const float* ln2b = (const float*)d_in[12];
    const float* W1   = (const float*)d_in[13];
    const float* b1   = (const float*)d_in[14];
    const float* W2   = (const float*)d_in[15];
    const float* b2   = (const float*)d_in[16];

    float* y_out   = (float*)d_out;
    float* mem_out = (float*)d_out + 4194304;

    // ===== d_out (32 MB fp32) as scratch, time-multiplexed =====
    char* dob = (char*)d_out;
    u16* attno     = (u16*)(dob + 0);
    u16* pe        = (u16*)(dob + (size_t)8  * 1048576);
    u16* rbuf_base = (u16*)(dob + (size_t)12 * 1048576);
    u16* rbuf      = rbuf_base + 80 * 1024;           // padded +/-80 rows
    char* dw = dob + (size_t)16 * 1048576 + 524288;   // 16.5 MB
    u16* WqT = (u16*)(dw);
    u16* WkT = (u16*)(dw + (size_t)2 * 1048576);
    u16* WvT = (u16*)(dw + (size_t)4 * 1048576);
    u16* WrT = (u16*)(dw + (size_t)6 * 1048576);
    u16* WoT = (u16*)(dw + (size_t)8 * 1048576);

    // ===== ws layout, extent 64 MB =====
    char* ws = (char*)d_ws;
    const size_t MB = 1u << 20;
    u16*  xn    = (u16*)(ws + 0 * MB);
    u16*  x2n   = (u16*)(ws + 0 * MB);
    u16*  W2T   = (u16*)(ws + 0 * MB);
    u16*  qu    = (u16*)(ws + 8 * MB);
    float* x2f  = (float*)(ws + 8 * MB);
    u16*  qv    = (u16*)(ws + 16 * MB);
    u16*  kcat  = (u16*)(ws + 24 * MB);
    u16*  ffh   = (u16*)(ws + 24 * MB);
    u16*  vcat  = (u16*)(ws + 40 * MB);
    u16*  memb  = (u16*)(ws + 56 * MB);
    u16*  W1T   = (u16*)(ws + 56 * MB);

    transpose5_kernel<<<dim3(32, 32, 5), 256, 0, stream>>>(Wq, Wk, Wv, Wr, Wo,
                                                           WqT, WkT, WvT, WrT, WoT);
    pe_kernel<<<8192, 256, 0, stream>>>(pe);
    convert_kernel<<<2048, 256, 0, stream>>>(mem, memb);
    ln_kernel<<<1024, 256, 0, stream>>>(x, ln1g, ln1b, xn);
    gemm64_kernel<0><<<dim3(32, 8), 256, 0, stream>>>(pe, WrT, rbuf, nullptr, nullptr, nullptr, nullptr, 2048, 1024, 1024);
    gemm64_kernel<1><<<dim3(64, 8), 256, 0, stream>>>(xn, WqT, qu, qv, bu, bv, nullptr, 4096, 1024, 1024);
    gemm_kv_kernel<<<dim3(64, 8), 256, 0, stream>>>(memb, xn, WkT, WvT, kcat, vcat);
    attn_kernel<<<1024, 256, 0, stream>>>(qu, qv, kcat, vcat, rbuf, attno);
    gemm64_kernel<2><<<dim3(64, 8), 256, 0, stream>>>(attno, WoT, x2f, nullptr, nullptr, nullptr, x, 4096, 1024, 1024);
    transpose_kernel<<<dim3(128, 32), 256, 0, stream>>>(W1, W1T, 1024, 4096);
    hipMemcpyAsync(mem_out, x, (size_t)4194304 * 4, hipMemcpyDeviceToDevice, stream);
    ln_kernel<<<1024, 256, 0, stream>>>(x2f, ln2g, ln2b, x2n);
    gemm128_kernel<3><<<dim3(32, 32), 256, 0, stream>>>(x2n, W1T, ffh, b1, 4096, 4096, 1024);
    transpose_kernel<<<dim3(32, 128), 256, 0, stream>>>(W2, W2T, 4096, 1024);
    gemm64_kernel<4><<<dim3(64, 8), 256, 0, stream>>>(ffh, W2T, y_out, nullptr, b2, nullptr, x2f, 4096, 1024, 4096);
    (void)in_sizes; (void)n_in; (void)out_size; (void)ws_size;
}